// Round 3
// baseline (671.705 us; speedup 1.0000x reference)
//
#include <hip/hip_runtime.h>

// DP5 integrator, MI355X — all-fp32 VALU correctness baseline.
// Recursion in rank-128 space vs G=W@U (prep); full-space corrections deferred
// to end-of-run via whole-run accumulators. Runtime dtype detection (bf16/fp32).

typedef unsigned short u16;
typedef unsigned int u32;

struct Tab {
  double a[7][7]; double b[7]; double A[7]; double XC[7][7]; double XF[7]; double cxc[7];
};
static constexpr Tab make_tab() {
  Tab t{};
  t.a[2][1]=1.0/5;
  t.a[3][1]=3.0/40;       t.a[3][2]=9.0/40;
  t.a[4][1]=44.0/45;      t.a[4][2]=-56.0/15;      t.a[4][3]=32.0/9;
  t.a[5][1]=19372.0/6561; t.a[5][2]=-25360.0/2187; t.a[5][3]=64448.0/6561; t.a[5][4]=-212.0/729;
  t.a[6][1]=9017.0/3168;  t.a[6][2]=-355.0/33;     t.a[6][3]=46732.0/5247; t.a[6][4]=49.0/176; t.a[6][5]=-5103.0/18656;
  t.b[1]=35.0/384; t.b[2]=0.0; t.b[3]=500.0/1113; t.b[4]=125.0/192; t.b[5]=-2187.0/6784; t.b[6]=11.0/84;
  for (int i=1;i<=6;++i){ double s=0; for(int j=1;j<i;++j) s+=t.a[i][j]; t.A[i]=s; }
  for (int i=1;i<=6;++i) for(int l=1;l<i;++l){ double s=0; for(int j=l+1;j<i;++j) s+=t.a[i][j]*t.a[j][l]; t.XC[i][l]=s; }
  for (int i=1;i<=6;++i){ double s=0; for(int j=1;j<i;++j) s+=t.a[i][j]*t.A[j]; t.XF[i]=s; }
  for (int j=1;j<=6;++j){ double s=0; for(int i=j+1;i<=6;++i) s+=t.b[i]*t.a[i][j]; t.cxc[j]=s; }
  return t;
}
static constexpr Tab TB = make_tab();

__device__ __forceinline__ float bf2f(u16 h){ union{u32 i;float f;}c; c.i=((u32)h)<<16; return c.f; }
__device__ __forceinline__ u16 f2bf(float f){ union{float f;u32 i;}c; c.f=f; u32 r=c.i+0x7FFFu+((c.i>>16)&1u); return (u16)(r>>16); }
__device__ __forceinline__ float ldin(const void* p, int i, bool f32){
  return f32 ? ((const float*)p)[i] : bf2f(((const u16*)p)[i]);
}
__device__ __forceinline__ void stout(void* p, int i, float v, bool f32){
  if (f32) ((float*)p)[i] = v; else ((u16*)p)[i] = f2bf(v);
}
__device__ __forceinline__ int decode_steps(const void* p){
  int v = *(const int*)p;
  if (v >= 1 && v <= 512) return v;
  float f = *(const float*)p;
  if (f >= 1.f && f <= 512.f) return (int)f;
  float bf = bf2f(*(const u16*)p);
  if (bf >= 1.f && bf <= 512.f) return (int)bf;
  return 8;
}

// ---------------- prep kernels ----------------
__global__ void k_zero(int* f){ if (threadIdx.x == 0) *f = 0; }

__global__ void k_det(const u16* p, int* flag){
  int i = blockIdx.x*256 + threadIdx.x;   // grid 64x256
  int bad = 0;
  for (int k = i; k < 2097152; k += 16384) {
    float v = bf2f(p[k]);
    if (!(fabsf(v) < 1e6f)) bad = 1;     // catches huge + inf + NaN
  }
  if (bad) atomicOr(flag, 1);
}

__global__ void k_conv(const void* U, const void* W, float* Uf, float* Wf, const int* flag){
  bool f32 = (*flag) != 0;
  int b = blockIdx.x, t = threadIdx.x;    // grid 512x256
  int i = (b & 255)*256 + t;              // 0..65535
  if (b < 256) Uf[i] = ldin(U, i, f32);
  else         Wf[i] = ldin(W, i, f32);
}

__global__ void k_gbuild(const float* Uf, const float* Wf, float* G){
  int r = blockIdx.x, c = threadIdx.x;    // grid 128x128
  float acc = 0.f;
  #pragma unroll 4
  for (int d = 0; d < 512; ++d) acc += Wf[r*512 + d] * Uf[d*128 + c];
  G[r*128 + c] = acc;
}

// ---------------- main kernel ----------------
// LDS (floats): Gs[16384] | bufs[16*516=8256] | Ps[16*132=2112]  => 107008 B
#define LDS_FLOATS (16384 + 8256 + 2112)

__global__ __launch_bounds__(256,1) void dp5_main(
    const void* xg, const void* vg, const void* fg, const void* stepsp,
    const float* __restrict__ Uf, const float* __restrict__ Wf,
    const float* __restrict__ Gw, const int* __restrict__ flagp, void* outg)
{
  extern __shared__ float lds[];
  float* Gs   = lds;
  float* bufs = lds + 16384;
  float* Ps   = lds + 16384 + 8256;

  const int tid = threadIdx.x;
  const int row = tid >> 4, cg = tid & 15, c0 = cg*8;
  const int rb  = blockIdx.x * 16;
  const bool f32 = (*flagp) != 0;
  const int S = decode_steps(stepsp);
  const float dt = 0.01f;

  // stage G into LDS
  #pragma unroll
  for (int k = 0; k < 16; ++k)
    ((float4*)Gs)[tid + 256*k] = ((const float4*)Gw)[tid + 256*k];

  // ---- projections xU0, vU0, fU0 (fp32 dot vs Uf) ----
  float xU0[8], vU0[8], fU0[8];
  auto project = [&](const void* src, float* out8){
    __syncthreads();
    #pragma unroll
    for (int k = 0; k < 32; ++k) {
      int idx = tid + 256*k, rr = idx >> 9, dd = idx & 511;
      bufs[rr*516 + dd] = ldin(src, (rb + rr)*512 + dd, f32);
    }
    __syncthreads();
    float a[8] = {0,0,0,0,0,0,0,0};
    for (int d = 0; d < 512; ++d) {
      float xv = bufs[row*516 + d];
      float4 u0 = *(const float4*)(Uf + d*128 + c0);
      float4 u1 = *(const float4*)(Uf + d*128 + c0 + 4);
      a[0] += xv*u0.x; a[1] += xv*u0.y; a[2] += xv*u0.z; a[3] += xv*u0.w;
      a[4] += xv*u1.x; a[5] += xv*u1.y; a[6] += xv*u1.z; a[7] += xv*u1.w;
    }
    #pragma unroll
    for (int j = 0; j < 8; ++j) out8[j] = a[j];
  };
  project(xg, xU0); project(vg, vU0); project(fg, fU0);
  __syncthreads();

  // ---- recursion in rank-128 space ----
  float cxU[8], cvU[8], kU[6][8], Rr[8], QXa[8];
  #pragma unroll
  for (int j = 0; j < 8; ++j) { cxU[j] = xU0[j]; cvU[j] = vU0[j]; Rr[j] = 0.f; QXa[j] = 0.f; }

  for (int s = 0; s < S; ++s) {
    float accX[8], accV[8], Pbs[8], Pxcs[8];
    #pragma unroll
    for (int j = 0; j < 8; ++j) { accX[j]=0.f; accV[j]=0.f; Pbs[j]=0.f; Pxcs[j]=0.f; }

    #pragma unroll
    for (int i = 1; i <= 6; ++i) {
      const float dtA   = dt*(float)TB.A[i];
      const float dt2XF = dt*dt*(float)TB.XF[i];
      const float bi    = (float)TB.b[i];
      const float ci    = (float)TB.cxc[i];
      float P8[8];
      #pragma unroll
      for (int j = 0; j < 8; ++j) {
        float vv = cvU[j] + dtA*fU0[j];
        float xx = cxU[j] + dtA*cvU[j] + dt2XF*fU0[j];
        #pragma unroll
        for (int l = 1; l < i; ++l) {
          vv += (dt*(float)TB.a[i][l]) * kU[l-1][j];
          xx += (dt*dt*(float)TB.XC[i][l]) * kU[l-1][j];
        }
        float p = vv*xx;
        P8[j] = p; Pbs[j] += bi*p; Pxcs[j] += ci*p;
      }
      *(float4*)(Ps + row*132 + c0)     = make_float4(P8[0],P8[1],P8[2],P8[3]);
      *(float4*)(Ps + row*132 + c0 + 4) = make_float4(P8[4],P8[5],P8[6],P8[7]);
      __syncthreads();

      float a8[8] = {0,0,0,0,0,0,0,0};
      for (int r = 0; r < 128; r += 4) {
        float4 p4 = *(const float4*)(Ps + row*132 + r);
        const float pr[4] = {p4.x, p4.y, p4.z, p4.w};
        #pragma unroll
        for (int rr = 0; rr < 4; ++rr) {
          float pv = pr[rr];
          float4 g0 = *(const float4*)(Gs + (r+rr)*128 + c0);
          float4 g1 = *(const float4*)(Gs + (r+rr)*128 + c0 + 4);
          a8[0] += pv*g0.x; a8[1] += pv*g0.y; a8[2] += pv*g0.z; a8[3] += pv*g0.w;
          a8[4] += pv*g1.x; a8[5] += pv*g1.y; a8[6] += pv*g1.z; a8[7] += pv*g1.w;
        }
      }
      #pragma unroll
      for (int j = 0; j < 8; ++j) {
        float kv = -a8[j];
        kU[i-1][j] = kv;
        accX[j] += ci*kv; accV[j] += bi*kv;
      }
      __syncthreads();
    }

    #pragma unroll
    for (int j = 0; j < 8; ++j) {
      float nx = cxU[j] + dt*cvU[j] + dt*dt*(accX[j] + 0.5f*fU0[j]);
      cvU[j] += dt*(accV[j] + fU0[j]);
      cxU[j]  = nx;
      QXa[j] += Rr[j] + Pxcs[j];
      Rr[j]  += Pbs[j];
    }
  }

  // ---- deferred full-space epilogue ----
  float* Rl  = bufs;          // 16 x 132
  float* QXl = bufs + 2112;   // 16 x 132
  *(float4*)(Rl  + row*132 + c0)     = make_float4(Rr[0],Rr[1],Rr[2],Rr[3]);
  *(float4*)(Rl  + row*132 + c0 + 4) = make_float4(Rr[4],Rr[5],Rr[6],Rr[7]);
  *(float4*)(QXl + row*132 + c0)     = make_float4(QXa[0],QXa[1],QXa[2],QXa[3]);
  *(float4*)(QXl + row*132 + c0 + 4) = make_float4(QXa[4],QXa[5],QXa[6],QXa[7]);
  __syncthreads();

  const float Sdt = (float)S * dt;
  const int d0 = cg * 32;
  for (int dj = 0; dj < 32; dj += 4) {
    int d = d0 + dj;
    float ab[4] = {0,0,0,0}, ax[4] = {0,0,0,0};
    for (int r = 0; r < 128; ++r) {
      float rv = Rl[row*132 + r], qv = QXl[row*132 + r];
      float4 wv = *(const float4*)(Wf + r*512 + d);
      ab[0] += rv*wv.x; ab[1] += rv*wv.y; ab[2] += rv*wv.z; ab[3] += rv*wv.w;
      ax[0] += qv*wv.x; ax[1] += qv*wv.y; ax[2] += qv*wv.z; ax[3] += qv*wv.w;
    }
    #pragma unroll
    for (int t = 0; t < 4; ++t) {
      int dd = d + t, off = (rb + row)*512 + dd;
      float x0 = ldin(xg, off, f32), v0 = ldin(vg, off, f32), f0 = ldin(fg, off, f32);
      stout(outg, off,           x0 + Sdt*v0 + 0.5f*Sdt*Sdt*f0 - dt*dt*ax[t], f32);
      stout(outg, 2097152 + off, v0 + Sdt*f0 - dt*ab[t], f32);
    }
  }
}

extern "C" void kernel_launch(void* const* d_in, const int* in_sizes, int n_in,
                              void* d_out, int out_size, void* d_ws, size_t ws_size,
                              hipStream_t stream) {
  char* ws = (char*)d_ws;
  int*   flag = (int*)ws;
  float* Uf = (float*)(ws + 4096);
  float* Wf = Uf + 65536;
  float* G  = Wf + 65536;   // needs ~594 KB of d_ws total

  k_zero<<<dim3(1),   dim3(64),  0, stream>>>(flag);
  k_det <<<dim3(64),  dim3(256), 0, stream>>>((const u16*)d_in[0], flag);
  k_conv<<<dim3(512), dim3(256), 0, stream>>>(d_in[3], d_in[4], Uf, Wf, flag);
  k_gbuild<<<dim3(128), dim3(128), 0, stream>>>(Uf, Wf, G);

  const int lds_bytes = LDS_FLOATS * 4;
  hipFuncSetAttribute((const void*)dp5_main,
                      hipFuncAttributeMaxDynamicSharedMemorySize, lds_bytes);
  dp5_main<<<dim3(256), dim3(256), lds_bytes, stream>>>(
      d_in[0], d_in[1], d_in[2], d_in[5], Uf, Wf, G, flag, d_out);
}

// Round 4
// 476.380 us; speedup vs baseline: 1.4100x; 1.4100x over previous
//
#include <hip/hip_runtime.h>

// DP5 integrator, MI355X — R3 fp32 baseline + MFMA P@G (3-way bf16 split, 6 products).
// Recursion in rank-128 space vs G=W@U; projections/epilogue unchanged fp32 VALU.

typedef short v8s __attribute__((ext_vector_type(8)));
typedef float v4f __attribute__((ext_vector_type(4)));
typedef unsigned short u16;
typedef unsigned int u32;

struct Tab {
  double a[7][7]; double b[7]; double A[7]; double XC[7][7]; double XF[7]; double cxc[7];
};
static constexpr Tab make_tab() {
  Tab t{};
  t.a[2][1]=1.0/5;
  t.a[3][1]=3.0/40;       t.a[3][2]=9.0/40;
  t.a[4][1]=44.0/45;      t.a[4][2]=-56.0/15;      t.a[4][3]=32.0/9;
  t.a[5][1]=19372.0/6561; t.a[5][2]=-25360.0/2187; t.a[5][3]=64448.0/6561; t.a[5][4]=-212.0/729;
  t.a[6][1]=9017.0/3168;  t.a[6][2]=-355.0/33;     t.a[6][3]=46732.0/5247; t.a[6][4]=49.0/176; t.a[6][5]=-5103.0/18656;
  t.b[1]=35.0/384; t.b[2]=0.0; t.b[3]=500.0/1113; t.b[4]=125.0/192; t.b[5]=-2187.0/6784; t.b[6]=11.0/84;
  for (int i=1;i<=6;++i){ double s=0; for(int j=1;j<i;++j) s+=t.a[i][j]; t.A[i]=s; }
  for (int i=1;i<=6;++i) for(int l=1;l<i;++l){ double s=0; for(int j=l+1;j<i;++j) s+=t.a[i][j]*t.a[j][l]; t.XC[i][l]=s; }
  for (int i=1;i<=6;++i){ double s=0; for(int j=1;j<i;++j) s+=t.a[i][j]*t.A[j]; t.XF[i]=s; }
  for (int j=1;j<=6;++j){ double s=0; for(int i=j+1;i<=6;++i) s+=t.b[i]*t.a[i][j]; t.cxc[j]=s; }
  return t;
}
static constexpr Tab TB = make_tab();

__device__ __forceinline__ float bf2f(u16 h){ union{u32 i;float f;}c; c.i=((u32)h)<<16; return c.f; }
__device__ __forceinline__ u16 f2bf(float f){ union{float f;u32 i;}c; c.f=f; u32 r=c.i+0x7FFFu+((c.i>>16)&1u); return (u16)(r>>16); }
__device__ __forceinline__ float ldin(const void* p, int i, bool f32){
  return f32 ? ((const float*)p)[i] : bf2f(((const u16*)p)[i]);
}
__device__ __forceinline__ void stout(void* p, int i, float v, bool f32){
  if (f32) ((float*)p)[i] = v; else ((u16*)p)[i] = f2bf(v);
}
__device__ __forceinline__ int decode_steps(const void* p){
  int v = *(const int*)p;
  if (v >= 1 && v <= 512) return v;
  float f = *(const float*)p;
  if (f >= 1.f && f <= 512.f) return (int)f;
  float bf = bf2f(*(const u16*)p);
  if (bf >= 1.f && bf <= 512.f) return (int)bf;
  return 8;
}
// 3-way split: round-bf16, round-bf16, trunc-bf16 -> captures >=24 mantissa bits
__device__ __forceinline__ void split3(float x, u16& h, u16& m, u16& l){
  union{float f;u32 u;} c; c.f = x;
  u32 rh = (c.u + 0x7FFFu + ((c.u>>16)&1u)) & 0xFFFF0000u;
  h = (u16)(rh >> 16);
  union{u32 u;float f;} ch; ch.u = rh;
  float r1 = x - ch.f;
  union{float f;u32 u;} c1; c1.f = r1;
  u32 rm = (c1.u + 0x7FFFu + ((c1.u>>16)&1u)) & 0xFFFF0000u;
  m = (u16)(rm >> 16);
  union{u32 u;float f;} cm; cm.u = rm;
  float r2 = r1 - cm.f;
  union{float f;u32 u;} c2; c2.f = r2;
  l = (u16)(c2.u >> 16);
}

// ws layout (bytes)
#define WS_FLAG 0
#define WS_UF   4096
#define WS_WF   (4096 + 262144)
#define WS_GH   (4096 + 524288)
#define WS_GM   (WS_GH + 32768)
#define WS_GL   (WS_GM + 32768)

// ---------------- prep kernels ----------------
__global__ void k_zero(int* f){ if (threadIdx.x == 0) *f = 0; }

__global__ void k_det(const u16* p, int* flag){
  int i = blockIdx.x*256 + threadIdx.x;   // grid 64x256
  int bad = 0;
  for (int k = i; k < 2097152; k += 131072) {   // 16 strided samples/thread
    float v = bf2f(p[k]);
    if (!(fabsf(v) < 1e6f)) bad = 1;
  }
  if (bad) atomicOr(flag, 1);
}

__global__ void k_conv(const void* U, const void* W, float* Uf, float* Wf, const int* flag){
  bool f32 = (*flag) != 0;
  int b = blockIdx.x, t = threadIdx.x;    // grid 512x256
  int i = (b & 255)*256 + t;
  if (b < 256) Uf[i] = ldin(U, i, f32);
  else         Wf[i] = ldin(W, i, f32);
}

// G = W@U, fp32, then 3-split into B-fragment-swizzled bf16 arrays
__global__ void k_gbuild(const float* Uf, const float* Wf, u16* gH, u16* gM, u16* gL){
  int r = blockIdx.x, c = threadIdx.x;    // grid 128x128
  float acc = 0.f;
  #pragma unroll 4
  for (int d = 0; d < 512; ++d) acc += Wf[r*512 + d] * Uf[d*128 + c];
  u16 h, m, l; split3(acc, h, m, l);
  // B-frag: B[k=kb*32+q*8+j][n=nb*16+cl] at slot ((nb*4+kb)*64 + q*16+cl)*8 + j
  int kb = r >> 5, q = (r >> 3) & 3, j = r & 7, nb = c >> 4, cl = c & 15;
  int idx = ((nb*4 + kb)*64 + q*16 + cl)*8 + j;
  gH[idx] = h; gM[idx] = m; gL[idx] = l;
}

// ---------------- main kernel ----------------
__global__ __launch_bounds__(256,1) void dp5_main(
    const void* xg, const void* vg, const void* fg, const void* stepsp,
    const float* __restrict__ Uf, const float* __restrict__ Wf,
    const u16* __restrict__ gH, const u16* __restrict__ gM, const u16* __restrict__ gL,
    const int* __restrict__ flagp, void* outg)
{
  __shared__ float bufs[16*516];                       // projections + epilogue
  __shared__ u16 PaH[16*136], PaM[16*136], PaL[16*136]; // P split A-tiles
  __shared__ float kUl[16*132];                        // kU C->row-layout bridge

  const int tid = threadIdx.x;
  const int row = tid >> 4, cg = tid & 15, c0 = cg*8;
  const int w    = tid >> 6;
  const int lane = tid & 63;
  const int q    = lane >> 4;
  const int c16  = lane & 15;
  const int rb  = blockIdx.x * 16;
  const bool f32 = (*flagp) != 0;
  const int S = decode_steps(stepsp);
  const float dt = 0.01f;

  // ---- G B-fragments into VGPRs: wave w owns output cols 32w..32w+31 (gnb=2w+nbw)
  v8s Gh[2][4], Gm[2][4], Gl[2][4];
  #pragma unroll
  for (int nbw = 0; nbw < 2; ++nbw)
    #pragma unroll
    for (int kb = 0; kb < 4; ++kb) {
      int off = (((2*w + nbw)*4 + kb)*64 + lane)*8;
      Gh[nbw][kb] = *(const v8s*)(gH + off);
      Gm[nbw][kb] = *(const v8s*)(gM + off);
      Gl[nbw][kb] = *(const v8s*)(gL + off);
    }

  // ---- projections xU0, vU0, fU0 (fp32, unchanged from R3) ----
  float xU0[8], vU0[8], fU0[8];
  auto project = [&](const void* src, float* out8){
    __syncthreads();
    #pragma unroll
    for (int k = 0; k < 32; ++k) {
      int idx = tid + 256*k, rr = idx >> 9, dd = idx & 511;
      bufs[rr*516 + dd] = ldin(src, (rb + rr)*512 + dd, f32);
    }
    __syncthreads();
    float a[8] = {0,0,0,0,0,0,0,0};
    for (int d = 0; d < 512; ++d) {
      float xv = bufs[row*516 + d];
      float4 u0 = *(const float4*)(Uf + d*128 + c0);
      float4 u1 = *(const float4*)(Uf + d*128 + c0 + 4);
      a[0] += xv*u0.x; a[1] += xv*u0.y; a[2] += xv*u0.z; a[3] += xv*u0.w;
      a[4] += xv*u1.x; a[5] += xv*u1.y; a[6] += xv*u1.z; a[7] += xv*u1.w;
    }
    #pragma unroll
    for (int j = 0; j < 8; ++j) out8[j] = a[j];
  };
  project(xg, xU0); project(vg, vU0); project(fg, fU0);
  __syncthreads();

  // ---- recursion in rank-128 space ----
  float cxU[8], cvU[8], kU[6][8], Rr[8], QXa[8];
  #pragma unroll
  for (int j = 0; j < 8; ++j) { cxU[j] = xU0[j]; cvU[j] = vU0[j]; Rr[j] = 0.f; QXa[j] = 0.f; }

  for (int s = 0; s < S; ++s) {
    float accX[8], accV[8], Pbs[8], Pxcs[8];
    #pragma unroll
    for (int j = 0; j < 8; ++j) { accX[j]=0.f; accV[j]=0.f; Pbs[j]=0.f; Pxcs[j]=0.f; }

    #pragma unroll
    for (int i = 1; i <= 6; ++i) {
      const float dtA   = dt*(float)TB.A[i];
      const float dt2XF = dt*dt*(float)TB.XF[i];
      const float bi    = (float)TB.b[i];
      const float ci    = (float)TB.cxc[i];
      // P in row-layout: thread owns P[row][c0..c0+7]
      v8s ph, pm, pl;
      #pragma unroll
      for (int j = 0; j < 8; ++j) {
        float vv = cvU[j] + dtA*fU0[j];
        float xx = cxU[j] + dtA*cvU[j] + dt2XF*fU0[j];
        #pragma unroll
        for (int l = 1; l < i; ++l) {
          vv += (dt*(float)TB.a[i][l]) * kU[l-1][j];
          xx += (dt*dt*(float)TB.XC[i][l]) * kU[l-1][j];
        }
        float p = vv*xx;
        Pbs[j] += bi*p; Pxcs[j] += ci*p;
        u16 hh, mm, ll; split3(p, hh, mm, ll);
        ph[j] = (short)hh; pm[j] = (short)mm; pl[j] = (short)ll;
      }
      *(v8s*)(PaH + row*136 + c0) = ph;
      *(v8s*)(PaM + row*136 + c0) = pm;
      *(v8s*)(PaL + row*136 + c0) = pl;
      __syncthreads();

      // kU_i = -(P @ G): 16x16x32 MFMA, 6 split products
      v4f ac0 = {0.f,0.f,0.f,0.f}, ac1 = {0.f,0.f,0.f,0.f};
      #pragma unroll
      for (int kb = 0; kb < 4; ++kb) {
        int ao = c16*136 + kb*32 + q*8;
        v8s aH = *(const v8s*)(PaH + ao);
        v8s aM = *(const v8s*)(PaM + ao);
        v8s aL = *(const v8s*)(PaL + ao);
        ac0 = __builtin_amdgcn_mfma_f32_16x16x32_bf16(aH, Gh[0][kb], ac0, 0,0,0);
        ac1 = __builtin_amdgcn_mfma_f32_16x16x32_bf16(aH, Gh[1][kb], ac1, 0,0,0);
        ac0 = __builtin_amdgcn_mfma_f32_16x16x32_bf16(aH, Gm[0][kb], ac0, 0,0,0);
        ac1 = __builtin_amdgcn_mfma_f32_16x16x32_bf16(aH, Gm[1][kb], ac1, 0,0,0);
        ac0 = __builtin_amdgcn_mfma_f32_16x16x32_bf16(aM, Gh[0][kb], ac0, 0,0,0);
        ac1 = __builtin_amdgcn_mfma_f32_16x16x32_bf16(aM, Gh[1][kb], ac1, 0,0,0);
        ac0 = __builtin_amdgcn_mfma_f32_16x16x32_bf16(aH, Gl[0][kb], ac0, 0,0,0);
        ac1 = __builtin_amdgcn_mfma_f32_16x16x32_bf16(aH, Gl[1][kb], ac1, 0,0,0);
        ac0 = __builtin_amdgcn_mfma_f32_16x16x32_bf16(aL, Gh[0][kb], ac0, 0,0,0);
        ac1 = __builtin_amdgcn_mfma_f32_16x16x32_bf16(aL, Gh[1][kb], ac1, 0,0,0);
        ac0 = __builtin_amdgcn_mfma_f32_16x16x32_bf16(aM, Gm[0][kb], ac0, 0,0,0);
        ac1 = __builtin_amdgcn_mfma_f32_16x16x32_bf16(aM, Gm[1][kb], ac1, 0,0,0);
      }
      // C-layout writeback (col=lane&15, row=4q+reg), negate
      #pragma unroll
      for (int r = 0; r < 4; ++r) {
        kUl[(4*q + r)*132 + 32*w + 0  + c16] = -ac0[r];
        kUl[(4*q + r)*132 + 32*w + 16 + c16] = -ac1[r];
      }
      __syncthreads();
      // read back in row-layout
      float4 k0 = *(const float4*)(kUl + row*132 + c0);
      float4 k1 = *(const float4*)(kUl + row*132 + c0 + 4);
      float kv8[8] = {k0.x,k0.y,k0.z,k0.w,k1.x,k1.y,k1.z,k1.w};
      #pragma unroll
      for (int j = 0; j < 8; ++j) {
        kU[i-1][j] = kv8[j];
        accX[j] += ci*kv8[j]; accV[j] += bi*kv8[j];
      }
    }

    #pragma unroll
    for (int j = 0; j < 8; ++j) {
      float nx = cxU[j] + dt*cvU[j] + dt*dt*(accX[j] + 0.5f*fU0[j]);
      cvU[j] += dt*(accV[j] + fU0[j]);
      cxU[j]  = nx;
      QXa[j] += Rr[j] + Pbs[j]*0.f + Pxcs[j];   // QXa += Rr + Pxcs
      Rr[j]  += Pbs[j];
    }
  }

  // ---- deferred full-space epilogue (unchanged from R3) ----
  __syncthreads();
  float* Rl  = bufs;          // 16 x 132
  float* QXl = bufs + 2112;   // 16 x 132
  *(float4*)(Rl  + row*132 + c0)     = make_float4(Rr[0],Rr[1],Rr[2],Rr[3]);
  *(float4*)(Rl  + row*132 + c0 + 4) = make_float4(Rr[4],Rr[5],Rr[6],Rr[7]);
  *(float4*)(QXl + row*132 + c0)     = make_float4(QXa[0],QXa[1],QXa[2],QXa[3]);
  *(float4*)(QXl + row*132 + c0 + 4) = make_float4(QXa[4],QXa[5],QXa[6],QXa[7]);
  __syncthreads();

  const float Sdt = (float)S * dt;
  const int d0 = cg * 32;
  for (int dj = 0; dj < 32; dj += 4) {
    int d = d0 + dj;
    float ab[4] = {0,0,0,0}, ax[4] = {0,0,0,0};
    for (int r = 0; r < 128; ++r) {
      float rv = Rl[row*132 + r], qv = QXl[row*132 + r];
      float4 wv = *(const float4*)(Wf + r*512 + d);
      ab[0] += rv*wv.x; ab[1] += rv*wv.y; ab[2] += rv*wv.z; ab[3] += rv*wv.w;
      ax[0] += qv*wv.x; ax[1] += qv*wv.y; ax[2] += qv*wv.z; ax[3] += qv*wv.w;
    }
    #pragma unroll
    for (int t = 0; t < 4; ++t) {
      int dd = d + t, off = (rb + row)*512 + dd;
      float x0 = ldin(xg, off, f32), v0 = ldin(vg, off, f32), f0 = ldin(fg, off, f32);
      stout(outg, off,           x0 + Sdt*v0 + 0.5f*Sdt*Sdt*f0 - dt*dt*ax[t], f32);
      stout(outg, 2097152 + off, v0 + Sdt*f0 - dt*ab[t], f32);
    }
  }
}

extern "C" void kernel_launch(void* const* d_in, const int* in_sizes, int n_in,
                              void* d_out, int out_size, void* d_ws, size_t ws_size,
                              hipStream_t stream) {
  char* ws = (char*)d_ws;
  int*   flag = (int*)(ws + WS_FLAG);
  float* Uf = (float*)(ws + WS_UF);
  float* Wf = (float*)(ws + WS_WF);
  u16*   gH = (u16*)(ws + WS_GH);
  u16*   gM = (u16*)(ws + WS_GM);
  u16*   gL = (u16*)(ws + WS_GL);

  k_zero<<<dim3(1),   dim3(64),  0, stream>>>(flag);
  k_det <<<dim3(64),  dim3(256), 0, stream>>>((const u16*)d_in[0], flag);
  k_conv<<<dim3(512), dim3(256), 0, stream>>>(d_in[3], d_in[4], Uf, Wf, flag);
  k_gbuild<<<dim3(128), dim3(128), 0, stream>>>(Uf, Wf, gH, gM, gL);

  dp5_main<<<dim3(256), dim3(256), 0, stream>>>(
      d_in[0], d_in[1], d_in[2], d_in[5], Uf, Wf, gH, gM, gL, flag, d_out);
}

// Round 6
// 358.903 us; speedup vs baseline: 1.8715x; 1.3273x over previous
//
#include <hip/hip_runtime.h>

// DP5 integrator, MI355X — fp32 problem (inputs/outputs float32, proven R4).
// 256 WGs x 1024 thr (16 waves/CU). Rank-128 recursion vs G=W@U:
//   stage loop: P (16x128) -> split3 bf16 -> MFMA vs G-frags (split3),
//   16 units = 8 col-blocks x 2 K-halves, fp32 LDS reduce. (R4-validated path.)
// Projections & deferred epilogue: fp32 VALU (R3-validated math).

typedef short v8s __attribute__((ext_vector_type(8)));
typedef float v4f __attribute__((ext_vector_type(4)));
typedef unsigned short u16;
typedef unsigned int u32;

struct Tab {
  double a[7][7]; double b[7]; double A[7]; double XC[7][7]; double XF[7]; double cxc[7];
};
static constexpr Tab make_tab() {
  Tab t{};
  t.a[2][1]=1.0/5;
  t.a[3][1]=3.0/40;       t.a[3][2]=9.0/40;
  t.a[4][1]=44.0/45;      t.a[4][2]=-56.0/15;      t.a[4][3]=32.0/9;
  t.a[5][1]=19372.0/6561; t.a[5][2]=-25360.0/2187; t.a[5][3]=64448.0/6561; t.a[5][4]=-212.0/729;
  t.a[6][1]=9017.0/3168;  t.a[6][2]=-355.0/33;     t.a[6][3]=46732.0/5247; t.a[6][4]=49.0/176; t.a[6][5]=-5103.0/18656;
  t.b[1]=35.0/384; t.b[2]=0.0; t.b[3]=500.0/1113; t.b[4]=125.0/192; t.b[5]=-2187.0/6784; t.b[6]=11.0/84;
  for (int i=1;i<=6;++i){ double s=0; for(int j=1;j<i;++j) s+=t.a[i][j]; t.A[i]=s; }
  for (int i=1;i<=6;++i) for(int l=1;l<i;++l){ double s=0; for(int j=l+1;j<i;++j) s+=t.a[i][j]*t.a[j][l]; t.XC[i][l]=s; }
  for (int i=1;i<=6;++i){ double s=0; for(int j=1;j<i;++j) s+=t.a[i][j]*t.A[j]; t.XF[i]=s; }
  for (int j=1;j<=6;++j){ double s=0; for(int i=j+1;i<=6;++i) s+=t.b[i]*t.a[i][j]; t.cxc[j]=s; }
  return t;
}
static constexpr Tab TB = make_tab();

__device__ __forceinline__ int decode_steps(const void* p){
  int v = *(const int*)p;
  if (v >= 1 && v <= 512) return v;
  float f = *(const float*)p;
  if (f >= 1.f && f <= 512.f) return (int)f;
  return 8;
}
// 3-way split of fp32 into bf16 components: round, round, trunc (>=24 bits)
__device__ __forceinline__ void split3(float x, u16& h, u16& m, u16& l){
  union{float f;u32 u;} c; c.f = x;
  u32 rh = (c.u + 0x7FFFu + ((c.u>>16)&1u)) & 0xFFFF0000u;
  h = (u16)(rh >> 16);
  union{u32 u;float f;} ch; ch.u = rh;
  float r1 = x - ch.f;
  union{float f;u32 u;} c1; c1.f = r1;
  u32 rm = (c1.u + 0x7FFFu + ((c1.u>>16)&1u)) & 0xFFFF0000u;
  m = (u16)(rm >> 16);
  union{u32 u;float f;} cm; cm.u = rm;
  float r2 = r1 - cm.f;
  union{float f;u32 u;} c2; c2.f = r2;
  l = (u16)(c2.u >> 16);
}

// ws byte offsets
#define WS_GH 0
#define WS_GM 32768
#define WS_GL 65536

// ---------------- prep: G = W@U, 3-split, B-frag swizzle ----------------
__global__ __launch_bounds__(128) void k_gbuild(const float* __restrict__ U,
                                                const float* __restrict__ W,
                                                u16* gH, u16* gM, u16* gL){
  int r = blockIdx.x, c = threadIdx.x;   // 128 x 128
  float acc = 0.f;
  #pragma unroll 4
  for (int d = 0; d < 512; ++d) acc += W[r*512 + d] * U[d*128 + c];
  u16 h, m, l; split3(acc, h, m, l);
  // B-frag: B[k=kb*32+q*8+j][n=nb*16+cl] at slot ((nb*4+kb)*64 + q*16+cl)*8 + j
  int kb = r >> 5, q = (r >> 3) & 3, j = r & 7, nb = c >> 4, cl = c & 15;
  int idx = ((nb*4 + kb)*64 + q*16 + cl)*8 + j;
  gH[idx] = h; gM[idx] = m; gL[idx] = l;
}

// ---------------- main ----------------
// LDS union: bufs 16x516 f32 (33024 B)  |  PaH/PaM/PaL 3x4352 + Pp0/Pp1 2x8448
#define LDS_BYTES 33024

__global__ __launch_bounds__(1024,1) void dp5_main(
    const float* __restrict__ xg, const float* __restrict__ vg,
    const float* __restrict__ fg, const void* stepsp,
    const float* __restrict__ Ug, const float* __restrict__ Wg,
    const u16* __restrict__ gH, const u16* __restrict__ gM, const u16* __restrict__ gL,
    float* __restrict__ outg)
{
  __shared__ __align__(16) char arena[LDS_BYTES];
  float* bufs = (float*)arena;            // projections / epilogue staging
  u16*   PaH  = (u16*)(arena);
  u16*   PaM  = (u16*)(arena + 4352);
  u16*   PaL  = (u16*)(arena + 8704);
  float* Pp0  = (float*)(arena + 13056);
  float* Pp1  = (float*)(arena + 21504);

  const int tid  = threadIdx.x;
  const int ww   = tid >> 6;        // wave 0..15
  const int lane = tid & 63;
  const int q    = lane >> 4;
  const int c16  = lane & 15;
  const int r    = ww;              // owner row 0..15
  const int c2   = lane*2;          // owner cols c2, c2+1
  const int nb   = ww & 7;          // MFMA unit: col block
  const int kh   = ww >> 3;         // MFMA unit: K half
  const int rb   = blockIdx.x * 16;
  const int S    = decode_steps(stepsp);
  const float dt = 0.01f;

  // G fragments for this unit: kb = 2*kh + kbi
  v8s Gf[2][3];
  #pragma unroll
  for (int kbi = 0; kbi < 2; ++kbi) {
    int off = ((nb*4 + 2*kh + kbi)*64 + lane)*8;
    Gf[kbi][0] = *(const v8s*)(gH + off);
    Gf[kbi][1] = *(const v8s*)(gM + off);
    Gf[kbi][2] = *(const v8s*)(gL + off);
  }

  // ---- projections xU0, vU0, fU0 (fp32 VALU): wave ww owns row r, lane owns 2 cols
  float xU0[2], vU0[2], fU0[2];
  {
    const float* srcs[3] = {xg, vg, fg};
    float* outs[3] = {xU0, vU0, fU0};
    for (int p = 0; p < 3; ++p) {
      #pragma unroll
      for (int k = 0; k < 8; ++k) {
        int idx = tid + 1024*k, rr = idx >> 9, dd = idx & 511;
        bufs[rr*516 + dd] = srcs[p][(rb + rr)*512 + dd];
      }
      __syncthreads();
      float a0 = 0.f, a1 = 0.f;
      for (int d = 0; d < 512; ++d) {
        float xv = bufs[r*516 + d];
        float2 uu = *(const float2*)(Ug + d*128 + c2);
        a0 += xv*uu.x; a1 += xv*uu.y;
      }
      outs[p][0] = a0; outs[p][1] = a1;
      __syncthreads();
    }
  }

  // ---- rank-128 recursion ----
  float cxU[2], cvU[2], kU[6][2], Rr[2], QXa[2];
  #pragma unroll
  for (int j = 0; j < 2; ++j) {
    cxU[j] = xU0[j]; cvU[j] = vU0[j]; Rr[j] = 0.f; QXa[j] = 0.f;
    #pragma unroll
    for (int l = 0; l < 6; ++l) kU[l][j] = 0.f;
  }

  for (int s = 0; s < S; ++s) {
    float accX[2], accV[2], Pbs[2], Pxcs[2];
    #pragma unroll
    for (int j = 0; j < 2; ++j) { accX[j]=0.f; accV[j]=0.f; Pbs[j]=0.f; Pxcs[j]=0.f; }

    #pragma unroll
    for (int i = 1; i <= 6; ++i) {
      const float dtA   = dt*(float)TB.A[i];
      const float dt2XF = dt*dt*(float)TB.XF[i];
      const float bi    = (float)TB.b[i];
      const float ci    = (float)TB.cxc[i];
      // phase1: owner computes P for its 2 cols, 3-splits, writes A-tiles
      {
        u16 hh[2], mm[2], ll[2];
        #pragma unroll
        for (int j = 0; j < 2; ++j) {
          float vv = cvU[j] + dtA*fU0[j];
          float xx = cxU[j] + dtA*cvU[j] + dt2XF*fU0[j];
          #pragma unroll
          for (int l = 1; l < i; ++l) {
            vv += (dt*(float)TB.a[i][l]) * kU[l-1][j];
            xx += (dt*dt*(float)TB.XC[i][l]) * kU[l-1][j];
          }
          float p = vv*xx;
          Pbs[j] += bi*p; Pxcs[j] += ci*p;
          split3(p, hh[j], mm[j], ll[j]);
        }
        ((u32*)PaH)[r*68 + lane] = (u32)hh[0] | ((u32)hh[1] << 16);
        ((u32*)PaM)[r*68 + lane] = (u32)mm[0] | ((u32)mm[1] << 16);
        ((u32*)PaL)[r*68 + lane] = (u32)ll[0] | ((u32)ll[1] << 16);
      }
      __syncthreads();
      // phase2: unit (nb,kh) MFMA over kb=2kh,2kh+1 (6 split products each)
      v4f a0 = {0.f,0.f,0.f,0.f}, a1 = {0.f,0.f,0.f,0.f};
      #pragma unroll
      for (int kbi = 0; kbi < 2; ++kbi) {
        int ao = c16*136 + (2*kh + kbi)*32 + q*8;
        v8s aH = *(const v8s*)(PaH + ao);
        v8s aM = *(const v8s*)(PaM + ao);
        v8s aL = *(const v8s*)(PaL + ao);
        v4f& ac = kbi ? a1 : a0;
        ac = __builtin_amdgcn_mfma_f32_16x16x32_bf16(aH, Gf[kbi][0], ac, 0,0,0);
        ac = __builtin_amdgcn_mfma_f32_16x16x32_bf16(aH, Gf[kbi][1], ac, 0,0,0);
        ac = __builtin_amdgcn_mfma_f32_16x16x32_bf16(aM, Gf[kbi][0], ac, 0,0,0);
        ac = __builtin_amdgcn_mfma_f32_16x16x32_bf16(aH, Gf[kbi][2], ac, 0,0,0);
        ac = __builtin_amdgcn_mfma_f32_16x16x32_bf16(aL, Gf[kbi][0], ac, 0,0,0);
        ac = __builtin_amdgcn_mfma_f32_16x16x32_bf16(aM, Gf[kbi][1], ac, 0,0,0);
      }
      {
        float* Pp = kh ? Pp1 : Pp0;
        #pragma unroll
        for (int i4 = 0; i4 < 4; ++i4)
          Pp[(4*q + i4)*132 + nb*16 + c16] = a0[i4] + a1[i4];
      }
      __syncthreads();
      // owner reduce: kv = -(Pp0+Pp1)
      #pragma unroll
      for (int j = 0; j < 2; ++j) {
        float kv = -(Pp0[r*132 + c2 + j] + Pp1[r*132 + c2 + j]);
        kU[i-1][j] = kv;
        accX[j] += ci*kv; accV[j] += bi*kv;
      }
    }

    #pragma unroll
    for (int j = 0; j < 2; ++j) {
      float nx = cxU[j] + dt*cvU[j] + dt*dt*(accX[j] + 0.5f*fU0[j]);
      cvU[j] += dt*(accV[j] + fU0[j]);
      cxU[j]  = nx;
      QXa[j] += Rr[j] + Pxcs[j];
      Rr[j]  += Pbs[j];
    }
  }

  // ---- deferred full-space epilogue (fp32 VALU) ----
  __syncthreads();   // all stage-loop Pp reads done before reuse
  float* Rl  = Pp0;  // 16 x 132
  float* QXl = Pp1;
  Rl[r*132 + c2]      = Rr[0];  Rl[r*132 + c2 + 1]  = Rr[1];
  QXl[r*132 + c2]     = QXa[0]; QXl[r*132 + c2 + 1] = QXa[1];
  __syncthreads();

  const float Sdt = (float)S * dt;
  const int rr = ww, cc0 = lane*8;
  float ab[8] = {0,0,0,0,0,0,0,0}, ax[8] = {0,0,0,0,0,0,0,0};
  for (int rk = 0; rk < 128; ++rk) {
    float rv = Rl[rr*132 + rk], qv = QXl[rr*132 + rk];
    float4 w0 = *(const float4*)(Wg + rk*512 + cc0);
    float4 w1 = *(const float4*)(Wg + rk*512 + cc0 + 4);
    ab[0] += rv*w0.x; ab[1] += rv*w0.y; ab[2] += rv*w0.z; ab[3] += rv*w0.w;
    ab[4] += rv*w1.x; ab[5] += rv*w1.y; ab[6] += rv*w1.z; ab[7] += rv*w1.w;
    ax[0] += qv*w0.x; ax[1] += qv*w0.y; ax[2] += qv*w0.z; ax[3] += qv*w0.w;
    ax[4] += qv*w1.x; ax[5] += qv*w1.y; ax[6] += qv*w1.z; ax[7] += qv*w1.w;
  }
  #pragma unroll
  for (int t = 0; t < 8; ++t) {
    int off = (rb + rr)*512 + cc0 + t;
    float x0 = xg[off], v0 = vg[off], f0 = fg[off];
    outg[off]           = x0 + Sdt*v0 + 0.5f*Sdt*Sdt*f0 - dt*dt*ax[t];
    outg[2097152 + off] = v0 + Sdt*f0 - dt*ab[t];
  }
}

extern "C" void kernel_launch(void* const* d_in, const int* in_sizes, int n_in,
                              void* d_out, int out_size, void* d_ws, size_t ws_size,
                              hipStream_t stream) {
  const float* x = (const float*)d_in[0];
  const float* v = (const float*)d_in[1];
  const float* f = (const float*)d_in[2];
  const float* U = (const float*)d_in[3];
  const float* W = (const float*)d_in[4];
  char* ws = (char*)d_ws;
  u16* gH = (u16*)(ws + WS_GH);
  u16* gM = (u16*)(ws + WS_GM);
  u16* gL = (u16*)(ws + WS_GL);

  k_gbuild<<<dim3(128), dim3(128), 0, stream>>>(U, W, gH, gM, gL);
  dp5_main<<<dim3(256), dim3(1024), 0, stream>>>(
      x, v, f, d_in[5], U, W, gH, gM, gL, (float*)d_out);
}

// Round 7
// 218.995 us; speedup vs baseline: 3.0672x; 1.6389x over previous
//
#include <hip/hip_runtime.h>

// DP5 integrator, MI355X. fp32 in/out. Rank-128 recursion vs G=W@U (split3 bf16
// MFMA, 6 products — R4/R6-validated). R7: 512 WGs x 512 thr (8 rows/WG,
// 2 WGs/CU for barrier-latency overlap); projections via MFMA (U split3 frags).

typedef short v8s __attribute__((ext_vector_type(8)));
typedef float v4f __attribute__((ext_vector_type(4)));
typedef unsigned short u16;
typedef unsigned int u32;

struct Tab {
  double a[7][7]; double b[7]; double A[7]; double XC[7][7]; double XF[7]; double cxc[7];
};
static constexpr Tab make_tab() {
  Tab t{};
  t.a[2][1]=1.0/5;
  t.a[3][1]=3.0/40;       t.a[3][2]=9.0/40;
  t.a[4][1]=44.0/45;      t.a[4][2]=-56.0/15;      t.a[4][3]=32.0/9;
  t.a[5][1]=19372.0/6561; t.a[5][2]=-25360.0/2187; t.a[5][3]=64448.0/6561; t.a[5][4]=-212.0/729;
  t.a[6][1]=9017.0/3168;  t.a[6][2]=-355.0/33;     t.a[6][3]=46732.0/5247; t.a[6][4]=49.0/176; t.a[6][5]=-5103.0/18656;
  t.b[1]=35.0/384; t.b[2]=0.0; t.b[3]=500.0/1113; t.b[4]=125.0/192; t.b[5]=-2187.0/6784; t.b[6]=11.0/84;
  for (int i=1;i<=6;++i){ double s=0; for(int j=1;j<i;++j) s+=t.a[i][j]; t.A[i]=s; }
  for (int i=1;i<=6;++i) for(int l=1;l<i;++l){ double s=0; for(int j=l+1;j<i;++j) s+=t.a[i][j]*t.a[j][l]; t.XC[i][l]=s; }
  for (int i=1;i<=6;++i){ double s=0; for(int j=1;j<i;++j) s+=t.a[i][j]*t.A[j]; t.XF[i]=s; }
  for (int j=1;j<=6;++j){ double s=0; for(int i=j+1;i<=6;++i) s+=t.b[i]*t.a[i][j]; t.cxc[j]=s; }
  return t;
}
static constexpr Tab TB = make_tab();

__device__ __forceinline__ int decode_steps(const void* p){
  int v = *(const int*)p;
  if (v >= 1 && v <= 512) return v;
  float f = *(const float*)p;
  if (f >= 1.f && f <= 512.f) return (int)f;
  return 8;
}
// 3-way split fp32 -> bf16 (round, round, trunc): captures >=24 mantissa bits
__device__ __forceinline__ void split3(float x, u16& h, u16& m, u16& l){
  union{float f;u32 u;} c; c.f = x;
  u32 rh = (c.u + 0x7FFFu + ((c.u>>16)&1u)) & 0xFFFF0000u;
  h = (u16)(rh >> 16);
  union{u32 u;float f;} ch; ch.u = rh;
  float r1 = x - ch.f;
  union{float f;u32 u;} c1; c1.f = r1;
  u32 rm = (c1.u + 0x7FFFu + ((c1.u>>16)&1u)) & 0xFFFF0000u;
  m = (u16)(rm >> 16);
  union{u32 u;float f;} cm; cm.u = rm;
  float r2 = r1 - cm.f;
  union{float f;u32 u;} c2; c2.f = r2;
  l = (u16)(c2.u >> 16);
}

// ws byte offsets
#define WS_GH 0
#define WS_GM 32768
#define WS_GL 65536
#define WS_UH 98304
#define WS_UM 229376
#define WS_UL 360448

// ---------------- prep ----------------
__global__ __launch_bounds__(128) void k_gbuild(const float* __restrict__ U,
                                                const float* __restrict__ W,
                                                u16* gH, u16* gM, u16* gL){
  int r = blockIdx.x, c = threadIdx.x;   // 128 x 128
  float acc = 0.f;
  #pragma unroll 4
  for (int d = 0; d < 512; ++d) acc += W[r*512 + d] * U[d*128 + c];
  u16 h, m, l; split3(acc, h, m, l);
  int kb = r >> 5, q = (r >> 3) & 3, j = r & 7, nb = c >> 4, cl = c & 15;
  int idx = ((nb*4 + kb)*64 + q*16 + cl)*8 + j;
  gH[idx] = h; gM[idx] = m; gL[idx] = l;
}

__global__ __launch_bounds__(1024) void k_usplit(const float* __restrict__ U,
                                                 u16* uH, u16* uM, u16* uL){
  int idx = blockIdx.x*1024 + threadIdx.x;  // grid 64: 65536 elems
  int r = idx >> 7, c = idx & 127;
  u16 h, m, l; split3(U[idx], h, m, l);
  int kb = r >> 5, q = (r >> 3) & 3, j = r & 7, nb = c >> 4, cl = c & 15;
  int slot = ((nb*16 + kb)*64 + q*16 + cl)*8 + j;   // 16 kb per nb (K=512)
  uH[slot] = h; uM[slot] = m; uL[slot] = l;
}

// ---------------- main ----------------
// arena layout (bytes):
//   proj A-tiles: AH 0 (16640) AM 16640 AL 33280   [16 x 520 u16, rows 8..15 zero]
//   stage tiles:  PaH 0 (4352) PaM 4352 PaL 8704 | Pp 13056 (8448 = 16x132 f32)
//   proj bridge:  PpF 49920 (8448)
#define A_AM 16640
#define A_AL 33280
#define A_PAM 4352
#define A_PAL 8704
#define A_PP  13056
#define A_PPF 49920
#define ARENA 58368

__global__ __launch_bounds__(512,4) void dp5_main(
    const float* __restrict__ xg, const float* __restrict__ vg,
    const float* __restrict__ fg, const void* stepsp,
    const float* __restrict__ Wg,
    const u16* __restrict__ uH, const u16* __restrict__ uM, const u16* __restrict__ uL,
    const u16* __restrict__ gH, const u16* __restrict__ gM, const u16* __restrict__ gL,
    float* __restrict__ outg)
{
  __shared__ __align__(16) char arena[ARENA];
  u16* AHp = (u16*)(arena);
  u16* AMp = (u16*)(arena + A_AM);
  u16* ALp = (u16*)(arena + A_AL);
  u16* PaH = (u16*)(arena);
  u16* PaM = (u16*)(arena + A_PAM);
  u16* PaL = (u16*)(arena + A_PAL);
  float* Pp  = (float*)(arena + A_PP);
  float* PpF = (float*)(arena + A_PPF);

  const int tid  = threadIdx.x;
  const int ww   = tid >> 6;        // wave 0..7 = owner row = MFMA nb
  const int lane = tid & 63;
  const int q    = lane >> 4;
  const int c16  = lane & 15;
  const int r    = ww;
  const int c2   = lane*2;
  const int nb   = ww;
  const int rb   = blockIdx.x * 8;
  const int S    = decode_steps(stepsp);
  const float dt = 0.01f;

  // G B-frags for this wave's nb: 4 kb x 3 splits (48 VGPRs)
  v8s Gf[4][3];
  #pragma unroll
  for (int kb = 0; kb < 4; ++kb) {
    int off = ((nb*4 + kb)*64 + lane)*8;
    Gf[kb][0] = *(const v8s*)(gH + off);
    Gf[kb][1] = *(const v8s*)(gM + off);
    Gf[kb][2] = *(const v8s*)(gL + off);
  }

  // zero rows 8..15 of proj A-tiles (once)
  #pragma unroll
  for (int a = 0; a < 3; ++a) {
    u32* z = (u32*)(arena + a*16640 + 8320);
    for (int k = tid; k < 2080; k += 512) z[k] = 0;
  }

  // ---- projections via MFMA: xU0, vU0, fU0 (owner layout) ----
  float xU0[2], vU0[2], fU0[2];
  {
    const float* srcs[3] = {xg, vg, fg};
    float* outs[3] = {xU0, vU0, fU0};
    for (int p = 0; p < 3; ++p) {
      // stage + split3 this WG's 8x512 tile: thread owns row ww, cols lane*8..+7
      {
        const float* src = srcs[p] + (rb + ww)*512 + lane*8;
        float4 s0 = *(const float4*)(src);
        float4 s1 = *(const float4*)(src + 4);
        float vals[8] = {s0.x,s0.y,s0.z,s0.w,s1.x,s1.y,s1.z,s1.w};
        u16 hh[8], mm[8], ll[8];
        #pragma unroll
        for (int j = 0; j < 8; ++j) split3(vals[j], hh[j], mm[j], ll[j]);
        uint4 pkH = { (u32)hh[0]|((u32)hh[1]<<16), (u32)hh[2]|((u32)hh[3]<<16),
                      (u32)hh[4]|((u32)hh[5]<<16), (u32)hh[6]|((u32)hh[7]<<16) };
        uint4 pkM = { (u32)mm[0]|((u32)mm[1]<<16), (u32)mm[2]|((u32)mm[3]<<16),
                      (u32)mm[4]|((u32)mm[5]<<16), (u32)mm[6]|((u32)mm[7]<<16) };
        uint4 pkL = { (u32)ll[0]|((u32)ll[1]<<16), (u32)ll[2]|((u32)ll[3]<<16),
                      (u32)ll[4]|((u32)ll[5]<<16), (u32)ll[6]|((u32)ll[7]<<16) };
        int o = ww*520 + lane*8;
        *(uint4*)(AHp + o) = pkH;
        *(uint4*)(AMp + o) = pkM;
        *(uint4*)(ALp + o) = pkL;
      }
      __syncthreads();
      // wave nb: 16 kb x 6 products
      v4f a0 = {0.f,0.f,0.f,0.f}, a1 = {0.f,0.f,0.f,0.f};
      #pragma unroll
      for (int kb = 0; kb < 16; ++kb) {
        int ao = c16*520 + kb*32 + q*8;
        v8s aH = *(const v8s*)(AHp + ao);
        v8s aM = *(const v8s*)(AMp + ao);
        v8s aL = *(const v8s*)(ALp + ao);
        int bo = ((nb*16 + kb)*64 + lane)*8;
        v8s bH = *(const v8s*)(uH + bo);
        v8s bM = *(const v8s*)(uM + bo);
        v8s bL = *(const v8s*)(uL + bo);
        a0 = __builtin_amdgcn_mfma_f32_16x16x32_bf16(aH, bH, a0, 0,0,0);
        a0 = __builtin_amdgcn_mfma_f32_16x16x32_bf16(aH, bM, a0, 0,0,0);
        a0 = __builtin_amdgcn_mfma_f32_16x16x32_bf16(aM, bH, a0, 0,0,0);
        a1 = __builtin_amdgcn_mfma_f32_16x16x32_bf16(aH, bL, a1, 0,0,0);
        a1 = __builtin_amdgcn_mfma_f32_16x16x32_bf16(aL, bH, a1, 0,0,0);
        a1 = __builtin_amdgcn_mfma_f32_16x16x32_bf16(aM, bM, a1, 0,0,0);
      }
      #pragma unroll
      for (int i4 = 0; i4 < 4; ++i4)
        PpF[(4*q + i4)*132 + nb*16 + c16] = a0[i4] + a1[i4];
      __syncthreads();
      outs[p][0] = PpF[r*132 + c2];
      outs[p][1] = PpF[r*132 + c2 + 1];
    }
  }
  __syncthreads();
  { // zero stage region (Pa tiles rows incl. 8..15 + Pp)
    u32* z = (u32*)arena;
    for (int k = tid; k < 5376; k += 512) z[k] = 0;
  }
  __syncthreads();

  // ---- rank-128 recursion (R6-validated dataflow) ----
  float cxU[2], cvU[2], kU[6][2], Rr[2], QXa[2];
  #pragma unroll
  for (int j = 0; j < 2; ++j) {
    cxU[j] = xU0[j]; cvU[j] = vU0[j]; Rr[j] = 0.f; QXa[j] = 0.f;
    #pragma unroll
    for (int l = 0; l < 6; ++l) kU[l][j] = 0.f;
  }

  for (int s = 0; s < S; ++s) {
    float accX[2], accV[2], Pbs[2], Pxcs[2];
    #pragma unroll
    for (int j = 0; j < 2; ++j) { accX[j]=0.f; accV[j]=0.f; Pbs[j]=0.f; Pxcs[j]=0.f; }

    #pragma unroll
    for (int i = 1; i <= 6; ++i) {
      const float dtA   = dt*(float)TB.A[i];
      const float dt2XF = dt*dt*(float)TB.XF[i];
      const float bi    = (float)TB.b[i];
      const float ci    = (float)TB.cxc[i];
      // phase1: owner computes P for 2 cols, split3, write A-tiles (rows 0..7)
      {
        u16 hh[2], mm[2], ll[2];
        #pragma unroll
        for (int j = 0; j < 2; ++j) {
          float vv = cvU[j] + dtA*fU0[j];
          float xx = cxU[j] + dtA*cvU[j] + dt2XF*fU0[j];
          #pragma unroll
          for (int l = 1; l < i; ++l) {
            vv += (dt*(float)TB.a[i][l]) * kU[l-1][j];
            xx += (dt*dt*(float)TB.XC[i][l]) * kU[l-1][j];
          }
          float p = vv*xx;
          Pbs[j] += bi*p; Pxcs[j] += ci*p;
          split3(p, hh[j], mm[j], ll[j]);
        }
        ((u32*)PaH)[r*68 + lane] = (u32)hh[0] | ((u32)hh[1] << 16);
        ((u32*)PaM)[r*68 + lane] = (u32)mm[0] | ((u32)mm[1] << 16);
        ((u32*)PaL)[r*68 + lane] = (u32)ll[0] | ((u32)ll[1] << 16);
      }
      __syncthreads();
      // phase2: wave nb, full K (4 kb x 6 products, two 12-chains)
      v4f a0 = {0.f,0.f,0.f,0.f}, a1 = {0.f,0.f,0.f,0.f};
      #pragma unroll
      for (int kb = 0; kb < 4; ++kb) {
        int ao = c16*136 + kb*32 + q*8;
        v8s aH = *(const v8s*)(PaH + ao);
        v8s aM = *(const v8s*)(PaM + ao);
        v8s aL = *(const v8s*)(PaL + ao);
        v4f& ac = (kb & 2) ? a1 : a0;
        ac = __builtin_amdgcn_mfma_f32_16x16x32_bf16(aH, Gf[kb][0], ac, 0,0,0);
        ac = __builtin_amdgcn_mfma_f32_16x16x32_bf16(aH, Gf[kb][1], ac, 0,0,0);
        ac = __builtin_amdgcn_mfma_f32_16x16x32_bf16(aM, Gf[kb][0], ac, 0,0,0);
        ac = __builtin_amdgcn_mfma_f32_16x16x32_bf16(aH, Gf[kb][2], ac, 0,0,0);
        ac = __builtin_amdgcn_mfma_f32_16x16x32_bf16(aL, Gf[kb][0], ac, 0,0,0);
        ac = __builtin_amdgcn_mfma_f32_16x16x32_bf16(aM, Gf[kb][1], ac, 0,0,0);
      }
      #pragma unroll
      for (int i4 = 0; i4 < 4; ++i4)
        Pp[(4*q + i4)*132 + nb*16 + c16] = a0[i4] + a1[i4];
      __syncthreads();
      // owner reduce
      #pragma unroll
      for (int j = 0; j < 2; ++j) {
        float kv = -Pp[r*132 + c2 + j];
        kU[i-1][j] = kv;
        accX[j] += ci*kv; accV[j] += bi*kv;
      }
    }

    #pragma unroll
    for (int j = 0; j < 2; ++j) {
      float nx = cxU[j] + dt*cvU[j] + dt*dt*(accX[j] + 0.5f*fU0[j]);
      cvU[j] += dt*(accV[j] + fU0[j]);
      cxU[j]  = nx;
      QXa[j] += Rr[j] + Pxcs[j];
      Rr[j]  += Pbs[j];
    }
  }

  // ---- deferred full-space epilogue (fp32 VALU, R6-validated) ----
  __syncthreads();
  float* Rl  = Pp;          // 8 x 132
  float* QXl = Pp + 1056;   // 8 x 132
  Rl[r*132 + c2]      = Rr[0];  Rl[r*132 + c2 + 1]  = Rr[1];
  QXl[r*132 + c2]     = QXa[0]; QXl[r*132 + c2 + 1] = QXa[1];
  __syncthreads();

  const float Sdt = (float)S * dt;
  const int rr = ww, cc0 = lane*8;
  float ab[8] = {0,0,0,0,0,0,0,0}, ax[8] = {0,0,0,0,0,0,0,0};
  #pragma unroll 4
  for (int rk = 0; rk < 128; ++rk) {
    float rv = Rl[rr*132 + rk], qv = QXl[rr*132 + rk];
    float4 w0 = *(const float4*)(Wg + rk*512 + cc0);
    float4 w1 = *(const float4*)(Wg + rk*512 + cc0 + 4);
    ab[0] += rv*w0.x; ab[1] += rv*w0.y; ab[2] += rv*w0.z; ab[3] += rv*w0.w;
    ab[4] += rv*w1.x; ab[5] += rv*w1.y; ab[6] += rv*w1.z; ab[7] += rv*w1.w;
    ax[0] += qv*w0.x; ax[1] += qv*w0.y; ax[2] += qv*w0.z; ax[3] += qv*w0.w;
    ax[4] += qv*w1.x; ax[5] += qv*w1.y; ax[6] += qv*w1.z; ax[7] += qv*w1.w;
  }
  #pragma unroll
  for (int t = 0; t < 8; ++t) {
    int off = (rb + rr)*512 + cc0 + t;
    float x0 = xg[off], v0 = vg[off], f0 = fg[off];
    outg[off]           = x0 + Sdt*v0 + 0.5f*Sdt*Sdt*f0 - dt*dt*ax[t];
    outg[2097152 + off] = v0 + Sdt*f0 - dt*ab[t];
  }
}

extern "C" void kernel_launch(void* const* d_in, const int* in_sizes, int n_in,
                              void* d_out, int out_size, void* d_ws, size_t ws_size,
                              hipStream_t stream) {
  const float* x = (const float*)d_in[0];
  const float* v = (const float*)d_in[1];
  const float* f = (const float*)d_in[2];
  const float* U = (const float*)d_in[3];
  const float* W = (const float*)d_in[4];
  char* ws = (char*)d_ws;
  u16* gH = (u16*)(ws + WS_GH);
  u16* gM = (u16*)(ws + WS_GM);
  u16* gL = (u16*)(ws + WS_GL);
  u16* uH = (u16*)(ws + WS_UH);
  u16* uM = (u16*)(ws + WS_UM);
  u16* uL = (u16*)(ws + WS_UL);

  k_gbuild<<<dim3(128), dim3(128), 0, stream>>>(U, W, gH, gM, gL);
  k_usplit<<<dim3(64), dim3(1024), 0, stream>>>(U, uH, uM, uL);
  dp5_main<<<dim3(512), dim3(512), 0, stream>>>(
      x, v, f, d_in[5], W, uH, uM, uL, gH, gM, gL, (float*)d_out);
}

// Round 8
// 190.282 us; speedup vs baseline: 3.5300x; 1.1509x over previous
//
#include <hip/hip_runtime.h>

// DP5 integrator, MI355X. fp32 in/out. Rank-128 recursion vs G=W@U.
// R8: 512 WGs x 512 thr. Wave nb owns small-space cols [16nb,16nb+16):
// MFMA C-layout -> spread state via __shfl (no LDS), ONE barrier/stage with
// double-buffered split3 P-tiles. G pre-negated (acc = kU). MFMA epilogue.

typedef short v8s __attribute__((ext_vector_type(8)));
typedef float v4f __attribute__((ext_vector_type(4)));
typedef unsigned short u16;
typedef unsigned int u32;

#define MFMA __builtin_amdgcn_mfma_f32_16x16x32_bf16

struct Tab {
  double a[7][7]; double b[7]; double A[7]; double XC[7][7]; double XF[7]; double cxc[7];
};
static constexpr Tab make_tab() {
  Tab t{};
  t.a[2][1]=1.0/5;
  t.a[3][1]=3.0/40;       t.a[3][2]=9.0/40;
  t.a[4][1]=44.0/45;      t.a[4][2]=-56.0/15;      t.a[4][3]=32.0/9;
  t.a[5][1]=19372.0/6561; t.a[5][2]=-25360.0/2187; t.a[5][3]=64448.0/6561; t.a[5][4]=-212.0/729;
  t.a[6][1]=9017.0/3168;  t.a[6][2]=-355.0/33;     t.a[6][3]=46732.0/5247; t.a[6][4]=49.0/176; t.a[6][5]=-5103.0/18656;
  t.b[1]=35.0/384; t.b[2]=0.0; t.b[3]=500.0/1113; t.b[4]=125.0/192; t.b[5]=-2187.0/6784; t.b[6]=11.0/84;
  for (int i=1;i<=6;++i){ double s=0; for(int j=1;j<i;++j) s+=t.a[i][j]; t.A[i]=s; }
  for (int i=1;i<=6;++i) for(int l=1;l<i;++l){ double s=0; for(int j=l+1;j<i;++j) s+=t.a[i][j]*t.a[j][l]; t.XC[i][l]=s; }
  for (int i=1;i<=6;++i){ double s=0; for(int j=1;j<i;++j) s+=t.a[i][j]*t.A[j]; t.XF[i]=s; }
  for (int j=1;j<=6;++j){ double s=0; for(int i=j+1;i<=6;++i) s+=t.b[i]*t.a[i][j]; t.cxc[j]=s; }
  return t;
}
static constexpr Tab TB = make_tab();

__device__ __forceinline__ int decode_steps(const void* p){
  int v = *(const int*)p;
  if (v >= 1 && v <= 512) return v;
  float f = *(const float*)p;
  if (f >= 1.f && f <= 512.f) return (int)f;
  return 8;
}
// 3-way split fp32 -> bf16 (round, round, trunc): captures >=24 mantissa bits
__device__ __forceinline__ void split3(float x, u16& h, u16& m, u16& l){
  union{float f;u32 u;} c; c.f = x;
  u32 rh = (c.u + 0x7FFFu + ((c.u>>16)&1u)) & 0xFFFF0000u;
  h = (u16)(rh >> 16);
  union{u32 u;float f;} ch; ch.u = rh;
  float r1 = x - ch.f;
  union{float f;u32 u;} c1; c1.f = r1;
  u32 rm = (c1.u + 0x7FFFu + ((c1.u>>16)&1u)) & 0xFFFF0000u;
  m = (u16)(rm >> 16);
  union{u32 u;float f;} cm; cm.u = rm;
  float r2 = r1 - cm.f;
  union{float f;u32 u;} c2; c2.f = r2;
  l = (u16)(c2.u >> 16);
}

// ws byte offsets
#define WS_GH 0
#define WS_GM 32768
#define WS_GL 65536
#define WS_UH 98304
#define WS_UM 229376
#define WS_UL 360448
#define WS_WH 491520
#define WS_WM 622592
#define WS_WL 753664

// ---------------- prep: one kernel, 640 blocks x 256 ----------------
__global__ __launch_bounds__(256) void k_prep(const float* __restrict__ U,
                                              const float* __restrict__ W,
                                              char* __restrict__ ws){
  u16* gH=(u16*)(ws+WS_GH); u16* gM=(u16*)(ws+WS_GM); u16* gL=(u16*)(ws+WS_GL);
  u16* uH=(u16*)(ws+WS_UH); u16* uM=(u16*)(ws+WS_UM); u16* uL=(u16*)(ws+WS_UL);
  u16* wH=(u16*)(ws+WS_WH); u16* wM=(u16*)(ws+WS_WM); u16* wL=(u16*)(ws+WS_WL);
  const int b = blockIdx.x, tid = threadIdx.x;
  if (b < 128) {                 // G = -(W@U) row b, 8-way ILP + 2-way LDS reduce
    __shared__ float part[128];
    int r = b, c = tid & 127, half = tid >> 7;
    int d0 = half*256;
    float a0=0,a1=0,a2=0,a3=0,a4=0,a5=0,a6=0,a7=0;
    for (int d = d0; d < d0+256; d += 8) {
      a0 += W[r*512+d  ]*U[(d  )*128+c];
      a1 += W[r*512+d+1]*U[(d+1)*128+c];
      a2 += W[r*512+d+2]*U[(d+2)*128+c];
      a3 += W[r*512+d+3]*U[(d+3)*128+c];
      a4 += W[r*512+d+4]*U[(d+4)*128+c];
      a5 += W[r*512+d+5]*U[(d+5)*128+c];
      a6 += W[r*512+d+6]*U[(d+6)*128+c];
      a7 += W[r*512+d+7]*U[(d+7)*128+c];
    }
    float acc = ((a0+a1)+(a2+a3)) + ((a4+a5)+(a6+a7));
    if (half) part[c] = acc;
    __syncthreads();
    if (!half) {
      float g = -(acc + part[c]);           // NEGATED: main acc = kU directly
      u16 h,m,l; split3(g,h,m,l);
      int kb=r>>5, q=(r>>3)&3, j=r&7, nb=c>>4, cl=c&15;
      int idx = ((nb*4+kb)*64 + q*16+cl)*8 + j;
      gH[idx]=h; gM[idx]=m; gL[idx]=l;
    }
  } else if (b < 384) {          // U split3 B-frags
    int idx = (b-128)*256 + tid;
    int r = idx >> 7, c = idx & 127;
    u16 h,m,l; split3(U[idx],h,m,l);
    int kb=r>>5,q=(r>>3)&3,j=r&7,nb=c>>4,cl=c&15;
    int slot = ((nb*16+kb)*64 + q*16+cl)*8 + j;
    uH[slot]=h; uM[slot]=m; uL[slot]=l;
  } else {                       // W split3 B-frags
    int idx = (b-384)*256 + tid;
    int r = idx >> 9, c = idx & 511;
    u16 h,m,l; split3(W[idx],h,m,l);
    int kb=r>>5,q=(r>>3)&3,j=r&7,nb=c>>4,cl=c&15;
    int slot = ((nb*4+kb)*64 + q*16+cl)*8 + j;
    wH[slot]=h; wM[slot]=m; wL[slot]=l;
  }
}

// ---------------- main ----------------
// arena: proj tiles t0/t1/t2 @0/16640/33280 (16x520 u16 each)
//        stage dbuf: buf0 @0, buf1 @13056 (each 3 x 16x136 u16 = 13056 B)
//        epilogue: R tiles @0, QX tiles @13056
#define ARENA 49920

__global__ __launch_bounds__(512,4) void dp5_main(
    const float* __restrict__ xg, const float* __restrict__ vg,
    const float* __restrict__ fg, const void* stepsp,
    const char* __restrict__ ws, float* __restrict__ outg)
{
  __shared__ __align__(16) char arena[ARENA];
  const u16* gH=(const u16*)(ws+WS_GH); const u16* gM=(const u16*)(ws+WS_GM);
  const u16* gL=(const u16*)(ws+WS_GL);
  const u16* uH=(const u16*)(ws+WS_UH); const u16* uM=(const u16*)(ws+WS_UM);
  const u16* uL=(const u16*)(ws+WS_UL);
  const u16* wHp=(const u16*)(ws+WS_WH); const u16* wMp=(const u16*)(ws+WS_WM);
  const u16* wLp=(const u16*)(ws+WS_WL);

  const int tid  = threadIdx.x;
  const int ww   = tid >> 6;          // wave = nb (col block owner)
  const int lane = tid & 63;
  const int q    = lane >> 4;
  const int c16  = lane & 15;
  const int nb   = ww;
  const int kcol = nb*16 + c16;       // this lane's small-space col / A k-index
  const int srcl = (q>>1)*16 + c16;   // shfl source for C->spread transform
  const bool odd = (q & 1);
  const int rb   = blockIdx.x * 8;
  const int S    = decode_steps(stepsp);
  const float dt = 0.01f;

  // G B-frags (negated): 4 kb x 3 splits
  v8s Gf[4][3];
  #pragma unroll
  for (int kb = 0; kb < 4; ++kb) {
    int off = ((nb*4 + kb)*64 + lane)*8;
    Gf[kb][0] = *(const v8s*)(gH + off);
    Gf[kb][1] = *(const v8s*)(gM + off);
    Gf[kb][2] = *(const v8s*)(gL + off);
  }

  // ---- projections: per field, split3-MFMA vs U-frags; output spread via shfl
  u16* t0 = (u16*)arena;
  u16* t1 = (u16*)(arena + 16640);
  u16* t2 = (u16*)(arena + 33280);
  float xU0[2], vU0[2], fU0[2];
  {
    const float* srcs[3] = {xg, vg, fg};
    float* outs[3] = {xU0, vU0, fU0};
    for (int p = 0; p < 3; ++p) {
      {
        const float* sp = srcs[p] + (rb + ww)*512 + lane*8;
        float4 s0 = *(const float4*)sp;
        float4 s1 = *(const float4*)(sp + 4);
        float vals[8] = {s0.x,s0.y,s0.z,s0.w,s1.x,s1.y,s1.z,s1.w};
        u16 hh[8], mm[8], ll[8];
        #pragma unroll
        for (int j = 0; j < 8; ++j) split3(vals[j], hh[j], mm[j], ll[j]);
        uint4 pkH = { (u32)hh[0]|((u32)hh[1]<<16), (u32)hh[2]|((u32)hh[3]<<16),
                      (u32)hh[4]|((u32)hh[5]<<16), (u32)hh[6]|((u32)hh[7]<<16) };
        uint4 pkM = { (u32)mm[0]|((u32)mm[1]<<16), (u32)mm[2]|((u32)mm[3]<<16),
                      (u32)mm[4]|((u32)mm[5]<<16), (u32)mm[6]|((u32)mm[7]<<16) };
        uint4 pkL = { (u32)ll[0]|((u32)ll[1]<<16), (u32)ll[2]|((u32)ll[3]<<16),
                      (u32)ll[4]|((u32)ll[5]<<16), (u32)ll[6]|((u32)ll[7]<<16) };
        int o = ww*520 + lane*8;
        *(uint4*)(t0 + o) = pkH;
        *(uint4*)(t1 + o) = pkM;
        *(uint4*)(t2 + o) = pkL;
      }
      __syncthreads();
      v4f a0={0,0,0,0}, a1={0,0,0,0}, a2={0,0,0,0}, a3={0,0,0,0};
      #pragma unroll
      for (int kb = 0; kb < 16; ++kb) {
        int ao = c16*520 + kb*32 + q*8;
        v8s aH = *(const v8s*)(t0 + ao);
        v8s aM = *(const v8s*)(t1 + ao);
        v8s aL = *(const v8s*)(t2 + ao);
        int bo = ((nb*16 + kb)*64 + lane)*8;
        v8s bH = *(const v8s*)(uH + bo);
        v8s bM = *(const v8s*)(uM + bo);
        v8s bL = *(const v8s*)(uL + bo);
        v4f& ac = ((kb&3)==0) ? a0 : ((kb&3)==1) ? a1 : ((kb&3)==2) ? a2 : a3;
        ac = MFMA(aH, bH, ac, 0,0,0);
        ac = MFMA(aH, bM, ac, 0,0,0);
        ac = MFMA(aM, bH, ac, 0,0,0);
        ac = MFMA(aH, bL, ac, 0,0,0);
        ac = MFMA(aL, bH, ac, 0,0,0);
        ac = MFMA(aM, bM, ac, 0,0,0);
      }
      float at0 = (a0[0]+a1[0])+(a2[0]+a3[0]);
      float at1 = (a0[1]+a1[1])+(a2[1]+a3[1]);
      float at2 = (a0[2]+a1[2])+(a2[2]+a3[2]);
      float at3 = (a0[3]+a1[3])+(a2[3]+a3[3]);
      float s0v = __shfl(at0, srcl, 64), s1v = __shfl(at1, srcl, 64);
      float s2v = __shfl(at2, srcl, 64), s3v = __shfl(at3, srcl, 64);
      outs[p][0] = odd ? s2v : s0v;    // row 2q
      outs[p][1] = odd ? s3v : s1v;    // row 2q+1
      __syncthreads();
    }
  }

  // ---- rank-128 recursion: spread state (lane owns rows 2q,2q+1 of col kcol)
  float cxU[2], cvU[2], kU6[6][2], Rr[2], QXa[2];
  #pragma unroll
  for (int j = 0; j < 2; ++j) {
    cxU[j] = xU0[j]; cvU[j] = vU0[j]; Rr[j] = 0.f; QXa[j] = 0.f;
    #pragma unroll
    for (int l = 0; l < 6; ++l) kU6[l][j] = 0.f;
  }

  int pb = 0;
  for (int s = 0; s < S; ++s) {
    float accX[2], accV[2], Pbs[2], Pxcs[2];
    #pragma unroll
    for (int j = 0; j < 2; ++j) { accX[j]=0.f; accV[j]=0.f; Pbs[j]=0.f; Pxcs[j]=0.f; }

    #pragma unroll
    for (int i = 1; i <= 6; ++i) {
      u16* bH = (u16*)(arena + (pb ? 13056 : 0));
      u16* bM = bH + 2176;
      u16* bL = bH + 4352;
      const float dtA   = dt*(float)TB.A[i];
      const float dt2XF = dt*dt*(float)TB.XF[i];
      const float bi    = (float)TB.b[i];
      const float ci    = (float)TB.cxc[i];
      // phase1: P for rows 2q,2q+1 of col kcol; split3; A-tile writes
      #pragma unroll
      for (int j = 0; j < 2; ++j) {
        float vv = cvU[j] + dtA*fU0[j];
        float xx = cxU[j] + dtA*cvU[j] + dt2XF*fU0[j];
        #pragma unroll
        for (int l = 1; l < i; ++l) {
          vv += (dt*(float)TB.a[i][l]) * kU6[l-1][j];
          xx += (dt*dt*(float)TB.XC[i][l]) * kU6[l-1][j];
        }
        float p = vv*xx;
        Pbs[j] += bi*p; Pxcs[j] += ci*p;
        u16 hh, mm, ll; split3(p, hh, mm, ll);
        int ad = (2*q + j)*136 + kcol;
        bH[ad] = hh; bM[ad] = mm; bL[ad] = ll;
      }
      __syncthreads();
      // MFMA: kU = P @ (-G); 4 independent 6-chains
      v4f a0={0,0,0,0}, a1={0,0,0,0}, a2={0,0,0,0}, a3={0,0,0,0};
      #pragma unroll
      for (int kb = 0; kb < 4; ++kb) {
        int ao = c16*136 + kb*32 + q*8;
        v8s aH = *(const v8s*)(bH + ao);
        v8s aM = *(const v8s*)(bM + ao);
        v8s aL = *(const v8s*)(bL + ao);
        v4f& ac = (kb==0) ? a0 : (kb==1) ? a1 : (kb==2) ? a2 : a3;
        ac = MFMA(aH, Gf[kb][0], ac, 0,0,0);
        ac = MFMA(aH, Gf[kb][1], ac, 0,0,0);
        ac = MFMA(aM, Gf[kb][0], ac, 0,0,0);
        ac = MFMA(aH, Gf[kb][2], ac, 0,0,0);
        ac = MFMA(aL, Gf[kb][0], ac, 0,0,0);
        ac = MFMA(aM, Gf[kb][1], ac, 0,0,0);
      }
      float at0 = (a0[0]+a1[0])+(a2[0]+a3[0]);
      float at1 = (a0[1]+a1[1])+(a2[1]+a3[1]);
      float at2 = (a0[2]+a1[2])+(a2[2]+a3[2]);
      float at3 = (a0[3]+a1[3])+(a2[3]+a3[3]);
      // C-layout -> spread (in-wave, no barrier)
      float s0v = __shfl(at0, srcl, 64), s1v = __shfl(at1, srcl, 64);
      float s2v = __shfl(at2, srcl, 64), s3v = __shfl(at3, srcl, 64);
      #pragma unroll
      for (int j = 0; j < 2; ++j) {
        float kv = j ? (odd ? s3v : s1v) : (odd ? s2v : s0v);
        kU6[i-1][j] = kv;
        accX[j] += ci*kv; accV[j] += bi*kv;
      }
      pb ^= 1;
    }

    #pragma unroll
    for (int j = 0; j < 2; ++j) {
      float nx = cxU[j] + dt*cvU[j] + dt*dt*(accX[j] + 0.5f*fU0[j]);
      cvU[j] += dt*(accV[j] + fU0[j]);
      cxU[j]  = nx;
      QXa[j] += Rr[j] + Pxcs[j];
      Rr[j]  += Pbs[j];
    }
  }

  // ---- epilogue: corrections via MFMA vs W-frags ----
  __syncthreads();                     // final-stage A-tile reads complete
  u16* RH = (u16*)arena;       u16* RM = RH + 2176; u16* RL = RH + 4352;
  u16* QH = (u16*)(arena + 13056); u16* QM = QH + 2176; u16* QL = QH + 4352;
  #pragma unroll
  for (int j = 0; j < 2; ++j) {
    int ad = (2*q + j)*136 + kcol;
    u16 h, m, l;
    split3(Rr[j], h, m, l);  RH[ad] = h; RM[ad] = m; RL[ad] = l;
    split3(QXa[j], h, m, l); QH[ad] = h; QM[ad] = m; QL[ad] = l;
  }
  __syncthreads();

  const float Sdt = (float)S * dt;
  #pragma unroll
  for (int cbi = 0; cbi < 4; ++cbi) {
    int cb = nb*4 + cbi;               // output col block 0..31
    v4f ab0={0,0,0,0}, ab1={0,0,0,0}, ax0={0,0,0,0}, ax1={0,0,0,0};
    #pragma unroll
    for (int kb = 0; kb < 4; ++kb) {
      int bo = ((cb*4 + kb)*64 + lane)*8;
      v8s bWH = *(const v8s*)(wHp + bo);
      v8s bWM = *(const v8s*)(wMp + bo);
      v8s bWL = *(const v8s*)(wLp + bo);
      int ao = c16*136 + kb*32 + q*8;
      v8s rH = *(const v8s*)(RH + ao);
      v8s rM = *(const v8s*)(RM + ao);
      v8s rL = *(const v8s*)(RL + ao);
      v8s qHs = *(const v8s*)(QH + ao);
      v8s qMs = *(const v8s*)(QM + ao);
      v8s qLs = *(const v8s*)(QL + ao);
      v4f& ab = (kb & 2) ? ab1 : ab0;
      v4f& ax = (kb & 2) ? ax1 : ax0;
      ab = MFMA(rH, bWH, ab, 0,0,0);
      ab = MFMA(rH, bWM, ab, 0,0,0);
      ab = MFMA(rM, bWH, ab, 0,0,0);
      ab = MFMA(rH, bWL, ab, 0,0,0);
      ab = MFMA(rL, bWH, ab, 0,0,0);
      ab = MFMA(rM, bWM, ab, 0,0,0);
      ax = MFMA(qHs, bWH, ax, 0,0,0);
      ax = MFMA(qHs, bWM, ax, 0,0,0);
      ax = MFMA(qMs, bWH, ax, 0,0,0);
      ax = MFMA(qHs, bWL, ax, 0,0,0);
      ax = MFMA(qLs, bWH, ax, 0,0,0);
      ax = MFMA(qMs, bWM, ax, 0,0,0);
    }
    if (q < 2) {                       // only C rows 0..7 are real
      #pragma unroll
      for (int i4 = 0; i4 < 4; ++i4) {
        float abv = ab0[i4] + ab1[i4];
        float axv = ax0[i4] + ax1[i4];
        int off = (rb + 4*q + i4)*512 + cb*16 + c16;
        float x0 = xg[off], v0 = vg[off], f0 = fg[off];
        outg[off]           = x0 + Sdt*v0 + 0.5f*Sdt*Sdt*f0 - dt*dt*axv;
        outg[2097152 + off] = v0 + Sdt*f0 - dt*abv;
      }
    }
  }
}

extern "C" void kernel_launch(void* const* d_in, const int* in_sizes, int n_in,
                              void* d_out, int out_size, void* d_ws, size_t ws_size,
                              hipStream_t stream) {
  const float* x = (const float*)d_in[0];
  const float* v = (const float*)d_in[1];
  const float* f = (const float*)d_in[2];
  const float* U = (const float*)d_in[3];
  const float* W = (const float*)d_in[4];
  char* ws = (char*)d_ws;

  k_prep<<<dim3(640), dim3(256), 0, stream>>>(U, W, ws);
  dp5_main<<<dim3(512), dim3(512), 0, stream>>>(
      x, v, f, d_in[5], ws, (float*)d_out);
}

// Round 10
// 157.333 us; speedup vs baseline: 4.2693x; 1.2094x over previous
//
#include <hip/hip_runtime.h>

// DP5 integrator, MI355X. fp32 in/out. Rank-128 recursion vs G=-(256·W@U).
// R10: R8 skeleton (512 WGs x 512 thr, one barrier/stage, dbuf P-tiles, shfl
// C->spread) with fp16-split2 numerics (3 products, denormal-safe via x256
// matrix prescale + x2048 lo-scale), x|v packed projections, R|QX packed epilogue.

typedef _Float16 v8h __attribute__((ext_vector_type(8)));
typedef float v4f __attribute__((ext_vector_type(4)));
typedef unsigned short u16;
typedef unsigned int u32;

#define MFMAH __builtin_amdgcn_mfma_f32_16x16x32_f16
#define INV2048 4.8828125e-4f
#define INV256  0.00390625f

struct Tab {
  double a[7][7]; double b[7]; double A[7]; double XC[7][7]; double XF[7]; double cxc[7];
};
static constexpr Tab make_tab() {
  Tab t{};
  t.a[2][1]=1.0/5;
  t.a[3][1]=3.0/40;       t.a[3][2]=9.0/40;
  t.a[4][1]=44.0/45;      t.a[4][2]=-56.0/15;      t.a[4][3]=32.0/9;
  t.a[5][1]=19372.0/6561; t.a[5][2]=-25360.0/2187; t.a[5][3]=64448.0/6561; t.a[5][4]=-212.0/729;
  t.a[6][1]=9017.0/3168;  t.a[6][2]=-355.0/33;     t.a[6][3]=46732.0/5247; t.a[6][4]=49.0/176; t.a[6][5]=-5103.0/18656;
  t.b[1]=35.0/384; t.b[2]=0.0; t.b[3]=500.0/1113; t.b[4]=125.0/192; t.b[5]=-2187.0/6784; t.b[6]=11.0/84;
  for (int i=1;i<=6;++i){ double s=0; for(int j=1;j<i;++j) s+=t.a[i][j]; t.A[i]=s; }
  for (int i=1;i<=6;++i) for(int l=1;l<i;++l){ double s=0; for(int j=l+1;j<i;++j) s+=t.a[i][j]*t.a[j][l]; t.XC[i][l]=s; }
  for (int i=1;i<=6;++i){ double s=0; for(int j=1;j<i;++j) s+=t.a[i][j]*t.A[j]; t.XF[i]=s; }
  for (int j=1;j<=6;++j){ double s=0; for (int i=j+1;i<=6;++i) s+=t.b[i]*t.a[i][j]; t.cxc[j]=s; }
  return t;
}
static constexpr Tab TB = make_tab();

__device__ __forceinline__ int decode_steps(const void* p){
  int v = *(const int*)p;
  if (v >= 1 && v <= 512) return v;
  float f = *(const float*)p;
  if (f >= 1.f && f <= 512.f) return (int)f;
  return 8;
}
// fp16 split2, lo scaled x2048 (keeps lo normal whenever |x| >= ~6e-5)
__device__ __forceinline__ void split2s(float x, _Float16& h, _Float16& l){
  h = (_Float16)x;
  l = (_Float16)((x - (float)h) * 2048.0f);
}

// ws offsets in HALF units
#define WS_GH 0        // 16384
#define WS_GL 16384
#define WS_UH 32768    // 65536
#define WS_UL 98304
#define WS_WH 163840   // 65536
#define WS_WL 229376

// ---------------- prep: 640 blocks x 256 ----------------
__global__ __launch_bounds__(256) void k_prep(const float* __restrict__ U,
                                              const float* __restrict__ W,
                                              _Float16* __restrict__ ws){
  const int b = blockIdx.x, tid = threadIdx.x;
  if (b < 128) {                 // G' = -256*(W@U), row r = b
    __shared__ float part[128];
    int r = b, c = tid & 127, half = tid >> 7, d0 = half*256;
    float a0=0,a1=0,a2=0,a3=0,a4=0,a5=0,a6=0,a7=0;
    for (int d = d0; d < d0+256; d += 8) {
      a0 += W[r*512+d  ]*U[(d  )*128+c];
      a1 += W[r*512+d+1]*U[(d+1)*128+c];
      a2 += W[r*512+d+2]*U[(d+2)*128+c];
      a3 += W[r*512+d+3]*U[(d+3)*128+c];
      a4 += W[r*512+d+4]*U[(d+4)*128+c];
      a5 += W[r*512+d+5]*U[(d+5)*128+c];
      a6 += W[r*512+d+6]*U[(d+6)*128+c];
      a7 += W[r*512+d+7]*U[(d+7)*128+c];
    }
    float acc = ((a0+a1)+(a2+a3)) + ((a4+a5)+(a6+a7));
    if (half) part[c] = acc;
    __syncthreads();
    if (!half) {
      float g = -256.f*(acc + part[c]);
      _Float16 h, l; split2s(g, h, l);
      int kb=r>>5, q=(r>>3)&3, j=r&7, nb=c>>4, cl=c&15;
      int idx = ((nb*4+kb)*64 + q*16+cl)*8 + j;
      ws[WS_GH + idx] = h; ws[WS_GL + idx] = l;
    }
  } else if (b < 384) {          // U' = 256*U B-frags
    int idx = (b-128)*256 + tid;
    int r = idx >> 7, c = idx & 127;
    _Float16 h, l; split2s(U[idx]*256.f, h, l);
    int kb=r>>5, q=(r>>3)&3, j=r&7, nb=c>>4, cl=c&15;
    int slot = ((nb*16+kb)*64 + q*16+cl)*8 + j;
    ws[WS_UH + slot] = h; ws[WS_UL + slot] = l;
  } else {                       // W' = 256*W B-frags
    int idx = (b-384)*256 + tid;
    int r = idx >> 9, c = idx & 511;
    _Float16 h, l; split2s(W[idx]*256.f, h, l);
    int kb=r>>5, q=(r>>3)&3, j=r&7, nb=c>>4, cl=c&15;
    int slot = ((nb*4+kb)*64 + q*16+cl)*8 + j;
    ws[WS_WH + slot] = h; ws[WS_WL + slot] = l;
  }
}

// ---------------- main ----------------
// arena (halfs): proj tH 0..8319 (16x520), tL 8320..16639
// stage dbuf: buf0 H@0 L@2176, buf1 H@4352 L@6528 (16x136 each)
// epilogue: RQh@0, RQl@2176
#define ARENA 33280

__global__ __launch_bounds__(512,4) void dp5_main(
    const float* __restrict__ xg, const float* __restrict__ vg,
    const float* __restrict__ fg, const void* stepsp,
    const _Float16* __restrict__ ws, float* __restrict__ outg)
{
  __shared__ __align__(16) char arena[ARENA];
  _Float16* base = (_Float16*)arena;
  const _Float16* uH = ws + WS_UH;
  const _Float16* uL = ws + WS_UL;
  const _Float16* wH = ws + WS_WH;
  const _Float16* wL = ws + WS_WL;

  const int tid  = threadIdx.x;
  const int ww   = tid >> 6;          // wave = nb
  const int lane = tid & 63;
  const int q    = lane >> 4;
  const int c16  = lane & 15;
  const int nb   = ww;
  const int kcol = nb*16 + c16;
  const int srcl = (q>>1)*16 + c16;
  const bool odd = (q & 1);
  const int rb   = blockIdx.x * 8;
  const int S    = decode_steps(stepsp);
  const float dt = 0.01f;

  // G' frags: 4 kb x {h,l}
  v8h Gh[4], Gl[4];
  #pragma unroll
  for (int kb = 0; kb < 4; ++kb) {
    int off = ((nb*4 + kb)*64 + lane)*8;
    Gh[kb] = *(const v8h*)(ws + WS_GH + off);
    Gl[kb] = *(const v8h*)(ws + WS_GL + off);
  }

  // ---- projections: pass0 = x|v packed (rows 0-7 | 8-15), pass1 = f ----
  _Float16* tH = base;
  _Float16* tL = base + 8320;
  const int r16 = tid >> 5, c0 = (tid & 31)*16;
  float xU0[2], vU0[2], fU0[2];
  for (int pass = 0; pass < 2; ++pass) {
    if (pass == 0 || r16 < 8) {
      const float* sp;
      if (pass == 0) sp = (r16 < 8) ? (xg + (rb + r16)*512) : (vg + (rb + r16 - 8)*512);
      else           sp = fg + (rb + r16)*512;
      sp += c0;
      float4 g0 = *(const float4*)(sp);
      float4 g1 = *(const float4*)(sp + 4);
      float4 g2 = *(const float4*)(sp + 8);
      float4 g3 = *(const float4*)(sp + 12);
      float vals[16] = {g0.x,g0.y,g0.z,g0.w, g1.x,g1.y,g1.z,g1.w,
                        g2.x,g2.y,g2.z,g2.w, g3.x,g3.y,g3.z,g3.w};
      v8h vh0, vh1, vl0, vl1;
      #pragma unroll
      for (int j = 0; j < 8; ++j) {
        _Float16 h, l;
        split2s(vals[j], h, l);     vh0[j] = h; vl0[j] = l;
        split2s(vals[8+j], h, l);   vh1[j] = h; vl1[j] = l;
      }
      int o = r16*520 + c0;
      *(v8h*)(tH + o) = vh0; *(v8h*)(tH + o + 8) = vh1;
      *(v8h*)(tL + o) = vl0; *(v8h*)(tL + o + 8) = vl1;
    }
    __syncthreads();
    v4f aH0={0,0,0,0}, aH1={0,0,0,0}, aC0={0,0,0,0}, aC1={0,0,0,0};
    #pragma unroll
    for (int kb = 0; kb < 16; ++kb) {
      int ao = c16*520 + kb*32 + q*8;
      v8h Ah = *(const v8h*)(tH + ao);
      v8h Al = *(const v8h*)(tL + ao);
      int bo = ((nb*16 + kb)*64 + lane)*8;
      v8h Bh = *(const v8h*)(uH + bo);
      v8h Bl = *(const v8h*)(uL + bo);
      if (kb & 1) {
        aH1 = MFMAH(Ah, Bh, aH1, 0,0,0);
        aC1 = MFMAH(Ah, Bl, aC1, 0,0,0);
        aC1 = MFMAH(Al, Bh, aC1, 0,0,0);
      } else {
        aH0 = MFMAH(Ah, Bh, aH0, 0,0,0);
        aC0 = MFMAH(Ah, Bl, aC0, 0,0,0);
        aC0 = MFMAH(Al, Bh, aC0, 0,0,0);
      }
    }
    float at0 = ((aH0[0]+aH1[0]) + (aC0[0]+aC1[0])*INV2048)*INV256;
    float at1 = ((aH0[1]+aH1[1]) + (aC0[1]+aC1[1])*INV2048)*INV256;
    float at2 = ((aH0[2]+aH1[2]) + (aC0[2]+aC1[2])*INV2048)*INV256;
    float at3 = ((aH0[3]+aH1[3]) + (aC0[3]+aC1[3])*INV2048)*INV256;
    if (pass == 0) {
      float sx0=__shfl(at0,srcl,64), sx1=__shfl(at1,srcl,64);
      float sx2=__shfl(at2,srcl,64), sx3=__shfl(at3,srcl,64);
      xU0[0] = odd ? sx2 : sx0; xU0[1] = odd ? sx3 : sx1;
      int srclv = srcl + 32;
      float sv0=__shfl(at0,srclv,64), sv1=__shfl(at1,srclv,64);
      float sv2=__shfl(at2,srclv,64), sv3=__shfl(at3,srclv,64);
      vU0[0] = odd ? sv2 : sv0; vU0[1] = odd ? sv3 : sv1;
    } else {
      float sf0=__shfl(at0,srcl,64), sf1=__shfl(at1,srcl,64);
      float sf2=__shfl(at2,srcl,64), sf3=__shfl(at3,srcl,64);
      fU0[0] = odd ? sf2 : sf0; fU0[1] = odd ? sf3 : sf1;
    }
    __syncthreads();
  }

  // ---- rank-128 recursion (spread: lane owns rows 2q,2q+1 of col kcol) ----
  float cxU[2], cvU[2], kU6[6][2], Rr[2], QXa[2];
  #pragma unroll
  for (int j = 0; j < 2; ++j) {
    cxU[j] = xU0[j]; cvU[j] = vU0[j]; Rr[j] = 0.f; QXa[j] = 0.f;
    #pragma unroll
    for (int l = 0; l < 6; ++l) kU6[l][j] = 0.f;
  }

  int pb = 0;
  for (int s = 0; s < S; ++s) {
    float accX[2], accV[2], Pbs[2], Pxcs[2];
    #pragma unroll
    for (int j = 0; j < 2; ++j) { accX[j]=0.f; accV[j]=0.f; Pbs[j]=0.f; Pxcs[j]=0.f; }

    #pragma unroll
    for (int i = 1; i <= 6; ++i) {
      _Float16* bH = base + (pb ? 4352 : 0);
      _Float16* bL = bH + 2176;
      const float dtA   = dt*(float)TB.A[i];
      const float dt2XF = dt*dt*(float)TB.XF[i];
      const float bi    = (float)TB.b[i];
      const float ci    = (float)TB.cxc[i];
      #pragma unroll
      for (int j = 0; j < 2; ++j) {
        float vv = cvU[j] + dtA*fU0[j];
        float xx = cxU[j] + dtA*cvU[j] + dt2XF*fU0[j];
        #pragma unroll
        for (int l = 1; l < i; ++l) {
          vv += (dt*(float)TB.a[i][l]) * kU6[l-1][j];
          xx += (dt*dt*(float)TB.XC[i][l]) * kU6[l-1][j];
        }
        float p = vv*xx;
        Pbs[j] += bi*p; Pxcs[j] += ci*p;
        _Float16 h, l2; split2s(p, h, l2);
        int ad = (2*q + j)*136 + kcol;
        bH[ad] = h; bL[ad] = l2;
      }
      __syncthreads();
      v4f aH={0,0,0,0}, aC0={0,0,0,0}, aC1={0,0,0,0};
      #pragma unroll
      for (int kb = 0; kb < 4; ++kb) {
        int ao = c16*136 + kb*32 + q*8;
        v8h Ah = *(const v8h*)(bH + ao);
        v8h Al = *(const v8h*)(bL + ao);
        aH = MFMAH(Ah, Gh[kb], aH, 0,0,0);
        if (kb & 1) {
          aC1 = MFMAH(Ah, Gl[kb], aC1, 0,0,0);
          aC1 = MFMAH(Al, Gh[kb], aC1, 0,0,0);
        } else {
          aC0 = MFMAH(Ah, Gl[kb], aC0, 0,0,0);
          aC0 = MFMAH(Al, Gh[kb], aC0, 0,0,0);
        }
      }
      float at0 = (aH[0] + (aC0[0]+aC1[0])*INV2048)*INV256;
      float at1 = (aH[1] + (aC0[1]+aC1[1])*INV2048)*INV256;
      float at2 = (aH[2] + (aC0[2]+aC1[2])*INV2048)*INV256;
      float at3 = (aH[3] + (aC0[3]+aC1[3])*INV2048)*INV256;
      float s0v=__shfl(at0,srcl,64), s1v=__shfl(at1,srcl,64);
      float s2v=__shfl(at2,srcl,64), s3v=__shfl(at3,srcl,64);
      #pragma unroll
      for (int j = 0; j < 2; ++j) {
        float kv = j ? (odd ? s3v : s1v) : (odd ? s2v : s0v);
        kU6[i-1][j] = kv;
        accX[j] += ci*kv; accV[j] += bi*kv;
      }
      pb ^= 1;
    }

    #pragma unroll
    for (int j = 0; j < 2; ++j) {
      float nx = cxU[j] + dt*cvU[j] + dt*dt*(accX[j] + 0.5f*fU0[j]);
      cvU[j] += dt*(accV[j] + fU0[j]);
      cxU[j]  = nx;
      QXa[j] += Rr[j] + Pxcs[j];
      Rr[j]  += Pbs[j];
    }
  }

  // ---- epilogue: packed A-tile rows 0-7 = R, rows 8-15 = QX ----
  __syncthreads();
  _Float16* RQh = base;
  _Float16* RQl = base + 2176;
  #pragma unroll
  for (int j = 0; j < 2; ++j) {
    _Float16 h, l;
    split2s(Rr[j], h, l);
    int ad = (2*q + j)*136 + kcol;
    RQh[ad] = h; RQl[ad] = l;
    split2s(QXa[j], h, l);
    int ad2 = (8 + 2*q + j)*136 + kcol;
    RQh[ad2] = h; RQl[ad2] = l;
  }
  __syncthreads();

  const float Sdt = (float)S * dt;
  #pragma unroll
  for (int cbi = 0; cbi < 4; ++cbi) {
    int cb = nb*4 + cbi;
    v4f aH={0,0,0,0}, aC0={0,0,0,0}, aC1={0,0,0,0};
    #pragma unroll
    for (int kb = 0; kb < 4; ++kb) {
      int bo = ((cb*4 + kb)*64 + lane)*8;
      v8h Bh = *(const v8h*)(wH + bo);
      v8h Bl = *(const v8h*)(wL + bo);
      int ao = c16*136 + kb*32 + q*8;
      v8h Ah = *(const v8h*)(RQh + ao);
      v8h Al = *(const v8h*)(RQl + ao);
      aH = MFMAH(Ah, Bh, aH, 0,0,0);
      if (kb & 1) {
        aC1 = MFMAH(Ah, Bl, aC1, 0,0,0);
        aC1 = MFMAH(Al, Bh, aC1, 0,0,0);
      } else {
        aC0 = MFMAH(Ah, Bl, aC0, 0,0,0);
        aC0 = MFMAH(Al, Bh, aC0, 0,0,0);
      }
    }
    float r0 = (aH[0] + (aC0[0]+aC1[0])*INV2048)*INV256;
    float r1 = (aH[1] + (aC0[1]+aC1[1])*INV2048)*INV256;
    float r2 = (aH[2] + (aC0[2]+aC1[2])*INV2048)*INV256;
    float r3 = (aH[3] + (aC0[3]+aC1[3])*INV2048)*INV256;
    // q<2 lanes hold R-corr (rows 0-7); partners (q+2) hold QX-corr same rows
    float o0 = __shfl_xor(r0, 32, 64);
    float o1 = __shfl_xor(r1, 32, 64);
    float o2 = __shfl_xor(r2, 32, 64);
    float o3 = __shfl_xor(r3, 32, 64);
    if (q < 2) {
      float abv[4] = {r0, r1, r2, r3};   // R @ W
      float axv[4] = {o0, o1, o2, o3};   // QX @ W
      #pragma unroll
      for (int i4 = 0; i4 < 4; ++i4) {
        int off = (rb + 4*q + i4)*512 + cb*16 + c16;
        float x0 = xg[off], v0 = vg[off], f0 = fg[off];
        outg[off]           = x0 + Sdt*v0 + 0.5f*Sdt*Sdt*f0 - dt*dt*axv[i4];
        outg[2097152 + off] = v0 + Sdt*f0 - dt*abv[i4];
      }
    }
  }
}

extern "C" void kernel_launch(void* const* d_in, const int* in_sizes, int n_in,
                              void* d_out, int out_size, void* d_ws, size_t ws_size,
                              hipStream_t stream) {
  const float* x = (const float*)d_in[0];
  const float* v = (const float*)d_in[1];
  const float* f = (const float*)d_in[2];
  const float* U = (const float*)d_in[3];
  const float* W = (const float*)d_in[4];
  _Float16* ws = (_Float16*)d_ws;

  k_prep<<<dim3(640), dim3(256), 0, stream>>>(U, W, ws);
  dp5_main<<<dim3(512), dim3(512), 0, stream>>>(
      x, v, f, d_in[5], ws, (float*)d_out);
}